// Round 13
// baseline (2485.714 us; speedup 1.0000x reference)
//
#include <hip/hip_runtime.h>
#include <math.h>

#define B_TOTAL 2048

// ---------------- helpers ----------------

__device__ __forceinline__ float bn_fold_scale(float g, float v) {
    return g * (float)(1.0 / sqrt((double)v + 1e-3));
}

// ---------------- conv1: [B,32,32,3] -> [B,16,16,32], 5x5 s2 SAME, relu+BN ----
__global__ __launch_bounds__(256) void k_conv1(
    const float* __restrict__ x, const float* __restrict__ w,
    const float* __restrict__ bias,
    const float* __restrict__ g, const float* __restrict__ be,
    const float* __restrict__ mm, const float* __restrict__ vv,
    float* __restrict__ out, int b0)
{
    __shared__ __align__(16) float sIn[3072];
    __shared__ __align__(16) float sW[2400];
    __shared__ __align__(16) float sB[32], sS[32], sBi[32];
    int t = threadIdx.x;
    const float* xin = x + (size_t)(b0 + blockIdx.x) * 3072;
    for (int i = t; i < 3072; i += 256) sIn[i] = xin[i];
    for (int i = t; i < 2400; i += 256) sW[i] = w[i];
    if (t < 32) {
        float sc = bn_fold_scale(g[t], vv[t]);
        sS[t] = sc; sBi[t] = be[t] - mm[t] * sc; sB[t] = bias[t];
    }
    __syncthreads();
    int oy = t >> 4, ox = t & 15;
    float patch[75];
#pragma unroll
    for (int kh = 0; kh < 5; ++kh) {
        int iy = 2 * oy - 1 + kh;
#pragma unroll
        for (int kw = 0; kw < 5; ++kw) {
            int ix = 2 * ox - 1 + kw;
            bool v = ((unsigned)iy < 32u) && ((unsigned)ix < 32u);
            int base = (iy * 32 + ix) * 3;
#pragma unroll
            for (int c = 0; c < 3; ++c)
                patch[(kh * 5 + kw) * 3 + c] = v ? sIn[base + c] : 0.0f;
        }
    }
    float acc[32];
#pragma unroll
    for (int i = 0; i < 32; ++i) acc[i] = 0.0f;
#pragma unroll 5
    for (int i = 0; i < 75; ++i) {
        float v = patch[i];
        const float* wr = &sW[i * 32];
#pragma unroll
        for (int q = 0; q < 8; ++q) {
            float wl[4];
            *(float4*)wl = *(const float4*)&wr[q * 4];
            acc[q*4+0] = fmaf(v, wl[0], acc[q*4+0]);
            acc[q*4+1] = fmaf(v, wl[1], acc[q*4+1]);
            acc[q*4+2] = fmaf(v, wl[2], acc[q*4+2]);
            acc[q*4+3] = fmaf(v, wl[3], acc[q*4+3]);
        }
    }
    float* o = out + ((size_t)blockIdx.x * 256 + t) * 32;
#pragma unroll
    for (int q = 0; q < 8; ++q) {
        float ov[4];
#pragma unroll
        for (int j = 0; j < 4; ++j) {
            int c = q * 4 + j;
            float r = fmaxf(acc[c] + sB[c], 0.0f);
            ov[j] = fmaf(r, sS[c], sBi[c]);
        }
        *(float4*)&o[q * 4] = *(float4*)ov;
    }
}

// ======== conv2 as per-tap GEMM: [B,16,16,32] -> [B,8,8,64] ==================
// (round-11 form: m-minor A, two float4 broadcasts per ci.)
__global__ __launch_bounds__(256) void k_c2g(
    const float* __restrict__ in, const float* __restrict__ w,
    const float* __restrict__ bias,
    const float* __restrict__ g, const float* __restrict__ be,
    const float* __restrict__ mm, const float* __restrict__ vv,
    float* __restrict__ out)
{
    __shared__ __align__(16) float sA[32 * 132];
    __shared__ __align__(16) float sW[32 * 64];
    __shared__ __align__(16) float sB[64], sS[64], sBi[64];
    int t = threadIdx.x;
    int img0 = blockIdx.x * 2;
    if (t < 64) {
        float sc = bn_fold_scale(g[t], vv[t]);
        sS[t] = sc; sBi[t] = be[t] - mm[t] * sc; sB[t] = bias[t];
    }
    const float* in0 = in + (size_t)img0 * 8192;
    int tx = t & 15, ty = t >> 4;
    float acc[8][4];
#pragma unroll
    for (int i = 0; i < 8; ++i)
#pragma unroll
        for (int j = 0; j < 4; ++j) acc[i][j] = 0.0f;

    for (int tap = 0; tap < 25; ++tap) {
        int kh = tap / 5, kw = tap - kh * 5;
        __syncthreads();
        for (int i = t; i < 4096; i += 256) {
            int ci = i & 31, m = i >> 5;
            int im = m >> 6, pix = m & 63;
            int oy = pix >> 3, ox = pix & 7;
            int iy = 2 * oy - 1 + kh, ix = 2 * ox - 1 + kw;
            float v = ((unsigned)iy < 16u && (unsigned)ix < 16u)
                          ? in0[((size_t)im * 256 + iy * 16 + ix) * 32 + ci] : 0.0f;
            sA[ci * 132 + m] = v;
        }
        for (int i = t; i < 2048; i += 256) {
            int co = i & 63, ci = i >> 6;
            sW[ci * 64 + co] = w[((size_t)tap * 32 + ci) * 64 + co];
        }
        __syncthreads();
#pragma unroll 4
        for (int ci = 0; ci < 32; ++ci) {
            float b[4];
            *(float4*)b = *(const float4*)&sW[ci * 64 + tx * 4];
            float a0[4], a1[4];
            *(float4*)a0 = *(const float4*)&sA[ci * 132 + ty * 8];
            *(float4*)a1 = *(const float4*)&sA[ci * 132 + ty * 8 + 4];
#pragma unroll
            for (int mi = 0; mi < 4; ++mi)
#pragma unroll
                for (int j = 0; j < 4; ++j) {
                    acc[mi][j]     = fmaf(a0[mi], b[j], acc[mi][j]);
                    acc[4 + mi][j] = fmaf(a1[mi], b[j], acc[4 + mi][j]);
                }
        }
    }
    int c0 = tx * 4;
    float sc[4], bi[4], bv[4];
#pragma unroll
    for (int j = 0; j < 4; ++j) { sc[j] = sS[c0 + j]; bi[j] = sBi[c0 + j]; bv[j] = sB[c0 + j]; }
#pragma unroll
    for (int mi = 0; mi < 8; ++mi) {
        int m = ty * 8 + mi;
        int im = m >> 6, pix = m & 63;
        float ov[4];
#pragma unroll
        for (int j = 0; j < 4; ++j) {
            float r = fmaxf(acc[mi][j] + bv[j], 0.0f);
            ov[j] = fmaf(r, sc[j], bi[j]);
        }
        *(float4*)&out[((size_t)(img0 + im) * 64 + pix) * 64 + c0] = *(float4*)ov;
    }
}

// ======== conv3 co-split GEMM: [B,8,8,64] -> [B,4,4,128] =====================
// Block = (4-img group, co-half): M = 64, N = 64 -> grid 2x larger (1024
// blocks = 4/CU) and LDS 34KB (sW halved). Per thread 4m x 4co; per ci:
// 1 A-float4 broadcast + 1 W-b128. Per-output order (tap asc, ci asc)
// unchanged.
__global__ __launch_bounds__(256) void k_c3g(
    const float* __restrict__ in, const float* __restrict__ w,
    const float* __restrict__ bias,
    const float* __restrict__ g, const float* __restrict__ be,
    const float* __restrict__ mm, const float* __restrict__ vv,
    float* __restrict__ out)
{
    __shared__ __align__(16) float sA[64 * 68];    // [ci][m], stride 68
    __shared__ __align__(16) float sW[64 * 64];    // [ci][co-half]
    __shared__ __align__(16) float sB[64], sS[64], sBi[64];
    int t = threadIdx.x;
    int img0 = blockIdx.x * 4;
    int coH = blockIdx.y * 64;
    if (t < 64) {
        int c = coH + t;
        float sc = bn_fold_scale(g[c], vv[c]);
        sS[t] = sc; sBi[t] = be[c] - mm[c] * sc; sB[t] = bias[c];
    }
    const float* in0 = in + (size_t)img0 * 4096;
    int tx = t & 15, ty = t >> 4;       // tx: co group (4), ty: m group (4)
    float acc[4][4];
#pragma unroll
    for (int i = 0; i < 4; ++i)
#pragma unroll
        for (int j = 0; j < 4; ++j) acc[i][j] = 0.0f;

    for (int tap = 0; tap < 25; ++tap) {
        int kh = tap / 5, kw = tap - kh * 5;
        __syncthreads();
        for (int i = t; i < 4096; i += 256) {
            int ci = i & 63, m = i >> 6;
            int im = m >> 4, pix = m & 15;
            int oy = pix >> 2, ox = pix & 3;
            int iy = 2 * oy - 1 + kh, ix = 2 * ox - 1 + kw;
            float v = ((unsigned)iy < 8u && (unsigned)ix < 8u)
                          ? in0[((size_t)im * 64 + iy * 8 + ix) * 64 + ci] : 0.0f;
            sA[ci * 68 + m] = v;
        }
        for (int i = t; i < 4096; i += 256) {
            int co = i & 63, ci = i >> 6;
            sW[ci * 64 + co] = w[((size_t)tap * 64 + ci) * 128 + coH + co];
        }
        __syncthreads();
#pragma unroll 4
        for (int ci = 0; ci < 64; ++ci) {
            float b[4];
            *(float4*)b = *(const float4*)&sW[ci * 64 + tx * 4];
            float a[4];
            *(float4*)a = *(const float4*)&sA[ci * 68 + ty * 4];
#pragma unroll
            for (int mi = 0; mi < 4; ++mi)
#pragma unroll
                for (int j = 0; j < 4; ++j)
                    acc[mi][j] = fmaf(a[mi], b[j], acc[mi][j]);
        }
    }
    int c0 = tx * 4;
#pragma unroll
    for (int mi = 0; mi < 4; ++mi) {
        int m = ty * 4 + mi;
        int im = m >> 4, pix = m & 15;
        float ov[4];
#pragma unroll
        for (int j = 0; j < 4; ++j) {
            float r = fmaxf(acc[mi][j] + sB[c0 + j], 0.0f);
            ov[j] = fmaf(r, sS[c0 + j], sBi[c0 + j]);
        }
        *(float4*)&out[((size_t)(img0 + im) * 16 + pix) * 128 + coH + c0] = *(float4*)ov;
    }
}

// ---------------- z partial GEMM: h3[Bc,2048] @ [wm|wv][2048,128] k-sliced ----
__global__ __launch_bounds__(256) void k_zpart(
    const float* __restrict__ A, const float* __restrict__ Wm,
    const float* __restrict__ Wv, float* __restrict__ part)
{
    __shared__ __align__(16) float sA[16 * 33];
    __shared__ __align__(16) float sW[32 * 256];
    int t = threadIdx.x;
    int img0 = blockIdx.x * 16;
    int k00 = blockIdx.y * 256;
    int li = t >> 4, cg = t & 15;
    float acc[16];
#pragma unroll
    for (int i = 0; i < 16; ++i) acc[i] = 0.0f;
    for (int k0 = 0; k0 < 256; k0 += 32) {
        for (int i = t; i < 512; i += 256) {
            int r = i >> 5, k = i & 31;
            sA[r * 33 + k] = A[(size_t)(img0 + r) * 2048 + k00 + k0 + k];
        }
        for (int i = t; i < 8192; i += 256) {
            int k = i >> 8, c = i & 255;
            float v = (c < 128) ? Wm[(size_t)(k00 + k0 + k) * 128 + c]
                                : Wv[(size_t)(k00 + k0 + k) * 128 + (c - 128)];
            sW[k * 256 + c] = v;
        }
        __syncthreads();
#pragma unroll 4
        for (int k = 0; k < 32; ++k) {
            float a = sA[li * 33 + k];
            const float* wr = &sW[k * 256];
#pragma unroll
            for (int q = 0; q < 4; ++q) {
                float wl[4];
                *(float4*)wl = *(const float4*)&wr[q * 64 + cg * 4];
                acc[q*4+0] = fmaf(a, wl[0], acc[q*4+0]);
                acc[q*4+1] = fmaf(a, wl[1], acc[q*4+1]);
                acc[q*4+2] = fmaf(a, wl[2], acc[q*4+2]);
                acc[q*4+3] = fmaf(a, wl[3], acc[q*4+3]);
            }
        }
        __syncthreads();
    }
    float* p = part + ((size_t)(img0 + li) * 8 + blockIdx.y) * 256;
#pragma unroll
    for (int q = 0; q < 4; ++q) {
        float4 v = make_float4(acc[q*4], acc[q*4+1], acc[q*4+2], acc[q*4+3]);
        *(float4*)&p[q * 64 + cg * 4] = v;
    }
}

// ---------------- z combine ----------------
__global__ __launch_bounds__(256) void k_zcombine(
    const float* __restrict__ part, const float* __restrict__ bm,
    const float* __restrict__ bv, const float* __restrict__ eps,
    float* __restrict__ z, int b0)
{
    int idx = blockIdx.x * 256 + threadIdx.x;
    int img = idx >> 7, c = idx & 127;
    const float* p = part + (size_t)img * 2048;
    float sm = 0.f, sv = 0.f;
#pragma unroll
    for (int s = 0; s < 8; ++s) { sm += p[s * 256 + c]; sv += p[s * 256 + 128 + c]; }
    float zm = fmaxf(sm + bm[c], 0.0f);
    float zlv = fmaxf(sv + bv[c], 0.0f);
    z[idx] = zm + expf(0.5f * zlv) * eps[(size_t)(b0 + img) * 128 + c];
}

// ---------------- generic K=128 GEMM: out = act(A[M,128]@W[128,N]+b), opt BN --
__global__ __launch_bounds__(256) void k_gemm128(
    const float* __restrict__ A, const float* __restrict__ W,
    const float* __restrict__ bias,
    const float* __restrict__ g, const float* __restrict__ be,
    const float* __restrict__ mm, const float* __restrict__ vv,
    float* __restrict__ out, int N, int M)
{
    __shared__ __align__(16) float sAt[64 * 68];
    __shared__ __align__(16) float sB[64 * 68];
    int t = threadIdx.x;
    int tx = t & 15, ty = t >> 4;
    int row0 = blockIdx.x * 64, col0 = blockIdx.y * 64;
    float acc[16];
#pragma unroll
    for (int i = 0; i < 16; ++i) acc[i] = 0.0f;
    for (int kc = 0; kc < 128; kc += 64) {
        for (int i = t; i < 4096; i += 256) {
            int r = i >> 6, k = i & 63;
            sAt[k * 68 + r] = (row0 + r < M) ? A[(size_t)(row0 + r) * 128 + kc + k] : 0.0f;
        }
        for (int i = t; i < 4096; i += 256) {
            int k = i >> 6, c = i & 63;
            sB[k * 68 + c] = W[(size_t)(kc + k) * N + col0 + c];
        }
        __syncthreads();
#pragma unroll 8
        for (int k = 0; k < 64; ++k) {
            float a[4], b[4];
            *(float4*)a = *(const float4*)&sAt[k * 68 + ty * 4];
            *(float4*)b = *(const float4*)&sB[k * 68 + tx * 4];
#pragma unroll
            for (int i = 0; i < 4; ++i)
#pragma unroll
                for (int j = 0; j < 4; ++j)
                    acc[i * 4 + j] = fmaf(a[i], b[j], acc[i * 4 + j]);
        }
        __syncthreads();
    }
    int c0 = col0 + tx * 4;
    float bvv[4];
    *(float4*)bvv = *(const float4*)&bias[c0];
    float sc[4], bi[4];
    bool has_bn = (g != nullptr);
    if (has_bn) {
#pragma unroll
        for (int j = 0; j < 4; ++j) {
            float s = bn_fold_scale(g[c0 + j], vv[c0 + j]);
            sc[j] = s; bi[j] = be[c0 + j] - mm[c0 + j] * s;
        }
    }
#pragma unroll
    for (int i = 0; i < 4; ++i) {
        int row = row0 + ty * 4 + i;
        if (row >= M) continue;
        float ov[4];
#pragma unroll
        for (int j = 0; j < 4; ++j) {
            float r = fmaxf(acc[i * 4 + j] + bvv[j], 0.0f);
            ov[j] = has_bn ? fmaf(r, sc[j], bi[j]) : r;
        }
        *(float4*)&out[(size_t)row * N + c0] = *(float4*)ov;
    }
}

// ====== convT2 img-pair fused: [B,8,8,128] -> [B,16,16,64], 4 img/block ======
template <int RY, int RX>
__device__ __forceinline__ void ct2g_body(
    const float* __restrict__ in0, const float* __restrict__ w,
    float* __restrict__ sA, float* __restrict__ sW,
    const float* __restrict__ sB, const float* __restrict__ sS,
    const float* __restrict__ sBi, float* __restrict__ out0)
{
    constexpr int NTY = RY ? 1 : 2;
    constexpr int NTX = RX ? 1 : 2;
    constexpr int TT = NTY * NTX;
    int t = threadIdx.x;
    int px0 = (t & 1) * 4;
    int py  = (t >> 1) & 7;
    int u   = (t >> 4) & 1;
    int ty  = t >> 5;            // 8 co-groups of 8
    int co0 = ty * 8;
    int imgA = 2 * u, imgB = 2 * u + 1;
    float acc0[4][8], acc1[4][8];
#pragma unroll
    for (int i = 0; i < 4; ++i)
#pragma unroll
        for (int j = 0; j < 8; ++j) { acc0[i][j] = 0.0f; acc1[i][j] = 0.0f; }

    for (int pass = 0; pass < 8; ++pass) {
        int ci0 = pass * 16;
        __syncthreads();
        for (int img = 0; img < 4; ++img) {
            const float* xin = in0 + (size_t)img * 8192;
            for (int i = t; i < 16 * 81; i += 256) {
                int ci = i & 15, pix = i >> 4;
                int r = pix / 9, c = pix - r * 9;
                int iy = r - 1, ix = c - 1;
                float v = (iy >= 0 && ix >= 0) ? xin[(iy * 8 + ix) * 128 + ci0 + ci] : 0.0f;
                sA[(img * 16 + ci) * 81 + pix] = v;
            }
        }
        for (int tb = 0; tb < TT; tb += 2) {
            if (tb) __syncthreads();
            for (int i = t; i < 2 * 16 * 64; i += 256) {
                int kk = i >> 6, co = i & 63;
                int tl = kk >> 4, ci = kk & 15;
                int tt = tb + tl; if (tt >= TT) tt = TT - 1;
                int kh = RY ? 1 : 2 * (tt / NTX);
                int kw = RX ? 1 : 2 * (tt % NTX);
                sW[kk * 64 + co] = w[((size_t)(kh * 3 + kw) * 128 + ci0 + ci) * 64 + co];
            }
            __syncthreads();
#pragma unroll
            for (int tl = 0; tl < 2; ++tl) {
                int tt = tb + tl;
                if (tt >= TT) break;
                int tY = tt / NTX, tX = tt % NTX;
                int r = RY ? (py + 1) : (py + tY);
                int cb = RX ? (px0 + 1) : (px0 + tX);
                int aB = r * 9 + cb;
#pragma unroll 4
                for (int ci = 0; ci < 16; ++ci) {
                    float b[8];
                    *(float4*)&b[0] = *(const float4*)&sW[(tl * 16 + ci) * 64 + co0];
                    *(float4*)&b[4] = *(const float4*)&sW[(tl * 16 + ci) * 64 + co0 + 4];
                    float a0[4], a1[4];
                    const float* pA = &sA[(imgA * 16 + ci) * 81 + aB];
                    const float* pB = &sA[(imgB * 16 + ci) * 81 + aB];
                    a0[0] = pA[0]; a0[1] = pA[1]; a0[2] = pA[2]; a0[3] = pA[3];
                    a1[0] = pB[0]; a1[1] = pB[1]; a1[2] = pB[2]; a1[3] = pB[3];
#pragma unroll
                    for (int i = 0; i < 4; ++i)
#pragma unroll
                        for (int j = 0; j < 8; ++j) {
                            acc0[i][j] = fmaf(a0[i], b[j], acc0[i][j]);
                            acc1[i][j] = fmaf(a1[i], b[j], acc1[i][j]);
                        }
                }
            }
        }
    }
#pragma unroll
    for (int l = 0; l < 2; ++l) {
        int img = 2 * u + l;
        float* oimg = out0 + (size_t)img * 16384;
#pragma unroll
        for (int i = 0; i < 4; ++i) {
            int oy = 2 * py + RY, ox = 2 * (px0 + i) + RX;
            float* o = oimg + (oy * 16 + ox) * 64 + co0;
            float ov0[4], ov1[4];
#pragma unroll
            for (int j = 0; j < 4; ++j) {
                int c = co0 + j;
                float r = fmaxf((l ? acc1[i][j] : acc0[i][j]) + sB[c], 0.0f);
                ov0[j] = fmaf(r, sS[c], sBi[c]);
            }
#pragma unroll
            for (int j = 0; j < 4; ++j) {
                int c = co0 + 4 + j;
                float r = fmaxf((l ? acc1[i][4 + j] : acc0[i][4 + j]) + sB[c], 0.0f);
                ov1[j] = fmaf(r, sS[c], sBi[c]);
            }
            *(float4*)o = *(float4*)ov0;
            *(float4*)(o + 4) = *(float4*)ov1;
        }
    }
}

__global__ __launch_bounds__(256, 4) void k_ct2g(
    const float* __restrict__ in, const float* __restrict__ w,
    const float* __restrict__ bias,
    const float* __restrict__ g, const float* __restrict__ be,
    const float* __restrict__ mm, const float* __restrict__ vv,
    float* __restrict__ out)
{
    __shared__ __align__(16) float sA[4 * 16 * 81];
    __shared__ __align__(16) float sW[2 * 16 * 64];
    __shared__ __align__(16) float sB[64], sS[64], sBi[64];
    int t = threadIdx.x;
    if (t < 64) {
        float sc = bn_fold_scale(g[t], vv[t]);
        sS[t] = sc; sBi[t] = be[t] - mm[t] * sc; sB[t] = bias[t];
    }
    const float* in0 = in + (size_t)blockIdx.x * 4 * 8192;
    float* out0 = out + (size_t)blockIdx.x * 4 * 16384;
    switch (blockIdx.y) {
        case 0:  ct2g_body<0,0>(in0, w, sA, sW, sB, sS, sBi, out0); break;
        case 1:  ct2g_body<0,1>(in0, w, sA, sW, sB, sS, sBi, out0); break;
        case 2:  ct2g_body<1,0>(in0, w, sA, sW, sB, sS, sBi, out0); break;
        default: ct2g_body<1,1>(in0, w, sA, sW, sB, sS, sBi, out0); break;
    }
}

// ====== convT3 img-pair fused: [B,16,16,64] -> [B,32,32,32], 2 img/block =====
template <int RY, int RX>
__device__ __forceinline__ void ct3g_body(
    const float* __restrict__ in0, const float* __restrict__ w,
    float* __restrict__ sA, float* __restrict__ sW,
    const float* __restrict__ sB, const float* __restrict__ sS,
    const float* __restrict__ sBi, float* __restrict__ out0)
{
    constexpr int NTY = RY ? 1 : 2;
    constexpr int NTX = RX ? 1 : 2;
    constexpr int TT = NTY * NTX;
    int t = threadIdx.x;
    int px0 = (t & 3) * 4;
    int py  = (t >> 2) & 15;
    int ty  = t >> 6;            // 4 co-groups of 8
    int co0 = ty * 8;
    float acc0[4][8], acc1[4][8];
#pragma unroll
    for (int i = 0; i < 4; ++i)
#pragma unroll
        for (int j = 0; j < 8; ++j) { acc0[i][j] = 0.0f; acc1[i][j] = 0.0f; }

    for (int pass = 0; pass < 8; ++pass) {
        int ci0 = pass * 8;
        __syncthreads();
        for (int img = 0; img < 2; ++img) {
            const float* xin = in0 + (size_t)img * 16384;
            for (int i = t; i < 8 * 289; i += 256) {
                int ci = i & 7, pix = i >> 3;
                int r = pix / 17, c = pix - r * 17;
                int iy = r - 1, ix = c - 1;
                float v = (iy >= 0 && ix >= 0) ? xin[(iy * 16 + ix) * 64 + ci0 + ci] : 0.0f;
                sA[(img * 8 + ci) * 289 + pix] = v;
            }
        }
        for (int tb = 0; tb < TT; tb += 2) {
            if (tb) __syncthreads();
            for (int i = t; i < 2 * 8 * 32; i += 256) {
                int kk = i >> 5, co = i & 31;
                int tl = kk >> 3, ci = kk & 7;
                int tt = tb + tl; if (tt >= TT) tt = TT - 1;
                int kh = RY ? 1 : 2 * (tt / NTX);
                int kw = RX ? 1 : 2 * (tt % NTX);
                sW[kk * 32 + co] = w[((size_t)(kh * 3 + kw) * 64 + ci0 + ci) * 32 + co];
            }
            __syncthreads();
#pragma unroll
            for (int tl = 0; tl < 2; ++tl) {
                int tt = tb + tl;
                if (tt >= TT) break;
                int tY = tt / NTX, tX = tt % NTX;
                int r = RY ? (py + 1) : (py + tY);
                int cb = RX ? (px0 + 1) : (px0 + tX);
                int aB = r * 17 + cb;
#pragma unroll 4
                for (int ci = 0; ci < 8; ++ci) {
                    float b[8];
                    *(float4*)&b[0] = *(const float4*)&sW[(tl * 8 + ci) * 32 + co0];
                    *(float4*)&b[4] = *(const float4*)&sW[(tl * 8 + ci) * 32 + co0 + 4];
                    float a0[4], a1[4];
                    const float* pA = &sA[ci * 289 + aB];
                    const float* pB = &sA[(8 + ci) * 289 + aB];
                    a0[0] = pA[0]; a0[1] = pA[1]; a0[2] = pA[2]; a0[3] = pA[3];
                    a1[0] = pB[0]; a1[1] = pB[1]; a1[2] = pB[2]; a1[3] = pB[3];
#pragma unroll
                    for (int i = 0; i < 4; ++i)
#pragma unroll
                        for (int j = 0; j < 8; ++j) {
                            acc0[i][j] = fmaf(a0[i], b[j], acc0[i][j]);
                            acc1[i][j] = fmaf(a1[i], b[j], acc1[i][j]);
                        }
                }
            }
        }
    }
#pragma unroll
    for (int l = 0; l < 2; ++l) {
        float* oimg = out0 + (size_t)l * 32768;
#pragma unroll
        for (int i = 0; i < 4; ++i) {
            int oy = 2 * py + RY, ox = 2 * (px0 + i) + RX;
            float* o = oimg + (oy * 32 + ox) * 32 + co0;
            float ov0[4], ov1[4];
#pragma unroll
            for (int j = 0; j < 4; ++j) {
                int c = co0 + j;
                float r = fmaxf((l ? acc1[i][j] : acc0[i][j]) + sB[c], 0.0f);
                ov0[j] = fmaf(r, sS[c], sBi[c]);
            }
#pragma unroll
            for (int j = 0; j < 4; ++j) {
                int c = co0 + 4 + j;
                float r = fmaxf((l ? acc1[i][4 + j] : acc0[i][4 + j]) + sB[c], 0.0f);
                ov1[j] = fmaf(r, sS[c], sBi[c]);
            }
            *(float4*)o = *(float4*)ov0;
            *(float4*)(o + 4) = *(float4*)ov1;
        }
    }
}

__global__ __launch_bounds__(256, 4) void k_ct3g(
    const float* __restrict__ in, const float* __restrict__ w,
    const float* __restrict__ bias,
    const float* __restrict__ g, const float* __restrict__ be,
    const float* __restrict__ mm, const float* __restrict__ vv,
    float* __restrict__ out)
{
    __shared__ __align__(16) float sA[2 * 8 * 289];
    __shared__ __align__(16) float sW[2 * 8 * 32];
    __shared__ __align__(16) float sB[32], sS[32], sBi[32];
    int t = threadIdx.x;
    if (t < 32) {
        float sc = bn_fold_scale(g[t], vv[t]);
        sS[t] = sc; sBi[t] = be[t] - mm[t] * sc; sB[t] = bias[t];
    }
    const float* in0 = in + (size_t)blockIdx.x * 2 * 16384;
    float* out0 = out + (size_t)blockIdx.x * 2 * 32768;
    switch (blockIdx.y) {
        case 0:  ct3g_body<0,0>(in0, w, sA, sW, sB, sS, sBi, out0); break;
        case 1:  ct3g_body<0,1>(in0, w, sA, sW, sB, sS, sBi, out0); break;
        case 2:  ct3g_body<1,0>(in0, w, sA, sW, sB, sS, sBi, out0); break;
        default: ct3g_body<1,1>(in0, w, sA, sW, sB, sS, sBi, out0); break;
    }
}

// ---------------- convT4 + sigmoid + error: [B,32,32,32] -> err [Bc,32,32] ----
__global__ __launch_bounds__(256) void k_convT4_err(
    const float* __restrict__ in, const float* __restrict__ w,
    const float* __restrict__ b, const float* __restrict__ x,
    float* __restrict__ err, int b0)
{
    __shared__ __align__(16) float sIn[32 * 342];
    int t = threadIdx.x;
    int quart = blockIdx.x, img = blockIdx.y;
    int r0 = quart * 8;
    const float* xin = in + (size_t)img * 32768;
    for (int i = t; i < 10880; i += 256) {
        int pix = i >> 5, ci = i & 31;
        int lr = pix / 34;
        int cx = pix - lr * 34 - 1;
        int gy = r0 - 1 + lr;
        float v = (((unsigned)gy < 32u) && ((unsigned)cx < 32u))
                      ? xin[(gy * 32 + cx) * 32 + ci] : 0.0f;
        sIn[ci * 342 + pix] = v;
    }
    __syncthreads();
    int ly = t >> 5, lx = t & 31;
    float a0 = 0.f, a1 = 0.f, a2 = 0.f;
#pragma unroll
    for (int kh = 0; kh < 3; ++kh)
#pragma unroll
        for (int kw = 0; kw < 3; ++kw) {
            int pix = (ly + kh) * 34 + (lx + kw);
            const float* wp = w + ((kh * 3 + kw) * 32) * 3;
#pragma unroll 4
            for (int ci = 0; ci < 32; ++ci) {
                float v = sIn[ci * 342 + pix];
                a0 = fmaf(v, wp[ci * 3 + 0], a0);
                a1 = fmaf(v, wp[ci * 3 + 1], a1);
                a2 = fmaf(v, wp[ci * 3 + 2], a2);
            }
        }
    float s0 = 1.0f / (1.0f + expf(-(a0 + b[0])));
    float s1 = 1.0f / (1.0f + expf(-(a1 + b[1])));
    float s2 = 1.0f / (1.0f + expf(-(a2 + b[2])));
    int oy = r0 + ly;
    size_t xi = (((size_t)(b0 + img) * 32 + oy) * 32 + lx) * 3;
    float d0 = x[xi + 0] - s0;
    float d1 = x[xi + 1] - s1;
    float d2 = x[xi + 2] - s2;
    err[(size_t)img * 1024 + oy * 32 + lx] = (d0 * d0 + d1 * d1 + d2 * d2) * (1.0f / 3.0f);
}

// ---------------- Otsu + mask (per-chunk) ----------------
__global__ __launch_bounds__(256) void k_otsu(
    const float* __restrict__ err, int* __restrict__ mask)
{
    __shared__ float sE[1024];
    __shared__ float sRed[4];
    __shared__ float sSig[96];
    __shared__ float sThr;
    int img = blockIdx.x, t = threadIdx.x;
    const float* e = err + (size_t)img * 1024;
    float part = 0.f;
    for (int i = t; i < 1024; i += 256) { float v = e[i]; sE[i] = v; part += v; }
    for (int o = 32; o; o >>= 1) part += __shfl_down(part, o);
    if ((t & 63) == 0) sRed[t >> 6] = part;
    __syncthreads();
    float tot = sRed[0] + sRed[1] + sRed[2] + sRed[3];
    if (t < 91) {
        float T = (float)((double)t * 0.01);
        int c = 0; float s = 0.f;
        for (int i = 0; i < 1024; ++i) {
            float v = sE[i];
            bool lt = v < T;
            c += lt ? 1 : 0;
            s += lt ? v : 0.0f;
        }
        float cf = (float)c;
        float p0 = cf * (1.0f / 1024.0f);
        float p1 = 1.0f - p0;
        float m0 = s / fmaxf(cf, 1.0f);
        float m1 = (tot - s) / fmaxf(1024.0f - cf, 1.0f);
        float d = m0 - m1;
        sSig[t] = (c > 0 && c < 1024) ? (p0 * p1) * (d * d) : 0.0f;
    }
    __syncthreads();
    if (t == 0) {
        float best = sSig[0]; int bk = 0;
        for (int k = 1; k < 91; ++k)
            if (sSig[k] > best) { best = sSig[k]; bk = k; }
        sThr = (float)((double)bk * 0.01);
    }
    __syncthreads();
    float thr = sThr;
    int* m = mask + (size_t)img * 1024;
    for (int i = t; i < 1024; i += 256) m[i] = (sE[i] < thr) ? 1 : 0;
}

// ---------------- launch ----------------
extern "C" void kernel_launch(void* const* d_in, const int* in_sizes, int n_in,
                              void* d_out, int out_size, void* d_ws, size_t ws_size,
                              hipStream_t stream)
{
    (void)in_sizes; (void)out_size;
    const float* p[46];
    bool flat = (n_in >= 46);
    if (flat) {
        for (int i = 0; i < 46; ++i) p[i] = (const float*)d_in[i];
    } else {
        int o = 0;
        int s = 0;
        auto leaf = [&](int count) {
            for (int j = 0; j < count; ++j) p[o++] = (const float*)d_in[s++];
        };
        auto bn4 = [&](int C) {
            const float* base = (const float*)d_in[s++];
            p[o++] = base; p[o++] = base + C; p[o++] = base + 2 * C; p[o++] = base + 3 * C;
        };
        leaf(2);            // x, eps_z
        leaf(2); bn4(32);   // e_w1, e_b1, e_bn1
        leaf(2); bn4(64);   // e_w2, e_b2, e_bn2
        leaf(2); bn4(128);  // e_w3, e_b3, e_bn3
        leaf(4);            // e_wm, e_bm, e_wv, e_bv
        leaf(2);            // d_wd, d_bd
        leaf(2); bn4(128);  // d_w1, d_b1, d_bn1
        leaf(2); bn4(64);   // d_w2, d_b2, d_bn2
        leaf(2); bn4(32);   // d_w3, d_b3, d_bn3
        leaf(2);            // d_w4, d_b4
    }
    const float* x      = p[0];
    const float* epsz   = p[1];
    const float* e_w1   = p[2];
    const float* e_b1   = p[3];
    const float* e_bn1g = p[4], *e_bn1b = p[5], *e_bn1m = p[6], *e_bn1v = p[7];
    const float* e_w2   = p[8];
    const float* e_b2   = p[9];
    const float* e_bn2g = p[10], *e_bn2b = p[11], *e_bn2m = p[12], *e_bn2v = p[13];
    const float* e_w3   = p[14];
    const float* e_b3   = p[15];
    const float* e_bn3g = p[16], *e_bn3b = p[17], *e_bn3m = p[18], *e_bn3v = p[19];
    const float* e_wm   = p[20];
    const float* e_bm   = p[21];
    const float* e_wv   = p[22];
    const float* e_bv   = p[23];
    const float* d_wd   = p[24];
    const float* d_bd   = p[25];
    const float* d_w1   = p[26];
    const float* d_b1   = p[27];
    const float* d_bn1g = p[28], *d_bn1b = p[29], *d_bn1m = p[30], *d_bn1v = p[31];
    const float* d_w2   = p[32];
    const float* d_b2   = p[33];
    const float* d_bn2g = p[34], *d_bn2b = p[35], *d_bn2m = p[36], *d_bn2v = p[37];
    const float* d_w3   = p[38];
    const float* d_b3   = p[39];
    const float* d_bn3g = p[40], *d_bn3b = p[41], *d_bn3m = p[42], *d_bn3v = p[43];
    const float* d_w4   = p[44];
    const float* d_b4   = p[45];
    int* mask = (int*)d_out;

    float* ws = (float*)d_ws;
    int Bc = B_TOTAL;
    while (Bc > 16) {
        size_t need = (size_t)Bc * 50304u * 4u;
        if (need <= ws_size) break;
        Bc >>= 1;
    }
    float* err = ws;
    float* z   = err + (size_t)Bc * 1024;
    float* P   = z + (size_t)Bc * 128;
    float* Q   = P + (size_t)Bc * 16384;

    for (int b0 = 0; b0 < B_TOTAL; b0 += Bc) {
        k_conv1<<<Bc, 256, 0, stream>>>(x, e_w1, e_b1, e_bn1g, e_bn1b, e_bn1m, e_bn1v, P, b0);
        k_c2g<<<Bc / 2, 256, 0, stream>>>(P, e_w2, e_b2, e_bn2g, e_bn2b, e_bn2m, e_bn2v, Q);
        k_c3g<<<dim3(Bc / 4, 2), 256, 0, stream>>>(Q, e_w3, e_b3, e_bn3g, e_bn3b, e_bn3m, e_bn3v, P);
        k_zpart<<<dim3(Bc / 16, 8), 256, 0, stream>>>(P, e_wm, e_wv, Q);
        k_zcombine<<<(Bc * 128) / 256, 256, 0, stream>>>(Q, e_bm, e_bv, epsz, z, b0);
        k_gemm128<<<dim3((Bc + 63) / 64, 128), 256, 0, stream>>>(z, d_wd, d_bd,
            nullptr, nullptr, nullptr, nullptr, P, 8192, Bc);
        k_gemm128<<<dim3(Bc, 2), 256, 0, stream>>>(P, d_w1, d_b1,
            d_bn1g, d_bn1b, d_bn1m, d_bn1v, Q, 128, Bc * 64);
        k_ct2g<<<dim3(Bc / 4, 4), 256, 0, stream>>>(Q, d_w2, d_b2, d_bn2g, d_bn2b, d_bn2m, d_bn2v, P);
        k_ct3g<<<dim3(Bc / 2, 4), 256, 0, stream>>>(P, d_w3, d_b3, d_bn3g, d_bn3b, d_bn3m, d_bn3v, Q);
        k_convT4_err<<<dim3(4, Bc), 256, 0, stream>>>(Q, d_w4, d_b4, x, err, b0);
        k_otsu<<<Bc, 256, 0, stream>>>(err, mask + (size_t)b0 * 1024);
    }
}

// Round 14
// 2100.909 us; speedup vs baseline: 1.1832x; 1.1832x over previous
//
#include <hip/hip_runtime.h>
#include <math.h>

#define B_TOTAL 2048

// ---------------- helpers ----------------

__device__ __forceinline__ float bn_fold_scale(float g, float v) {
    return g * (float)(1.0 / sqrt((double)v + 1e-3));
}

// ---------------- conv1: [B,32,32,3] -> [B,16,16,32], 5x5 s2 SAME, relu+BN ----
__global__ __launch_bounds__(256) void k_conv1(
    const float* __restrict__ x, const float* __restrict__ w,
    const float* __restrict__ bias,
    const float* __restrict__ g, const float* __restrict__ be,
    const float* __restrict__ mm, const float* __restrict__ vv,
    float* __restrict__ out, int b0)
{
    __shared__ __align__(16) float sIn[3072];
    __shared__ __align__(16) float sW[2400];
    __shared__ __align__(16) float sB[32], sS[32], sBi[32];
    int t = threadIdx.x;
    const float* xin = x + (size_t)(b0 + blockIdx.x) * 3072;
    for (int i = t; i < 3072; i += 256) sIn[i] = xin[i];
    for (int i = t; i < 2400; i += 256) sW[i] = w[i];
    if (t < 32) {
        float sc = bn_fold_scale(g[t], vv[t]);
        sS[t] = sc; sBi[t] = be[t] - mm[t] * sc; sB[t] = bias[t];
    }
    __syncthreads();
    int oy = t >> 4, ox = t & 15;
    float patch[75];
#pragma unroll
    for (int kh = 0; kh < 5; ++kh) {
        int iy = 2 * oy - 1 + kh;
#pragma unroll
        for (int kw = 0; kw < 5; ++kw) {
            int ix = 2 * ox - 1 + kw;
            bool v = ((unsigned)iy < 32u) && ((unsigned)ix < 32u);
            int base = (iy * 32 + ix) * 3;
#pragma unroll
            for (int c = 0; c < 3; ++c)
                patch[(kh * 5 + kw) * 3 + c] = v ? sIn[base + c] : 0.0f;
        }
    }
    float acc[32];
#pragma unroll
    for (int i = 0; i < 32; ++i) acc[i] = 0.0f;
#pragma unroll 5
    for (int i = 0; i < 75; ++i) {
        float v = patch[i];
        const float* wr = &sW[i * 32];
#pragma unroll
        for (int q = 0; q < 8; ++q) {
            float wl[4];
            *(float4*)wl = *(const float4*)&wr[q * 4];
            acc[q*4+0] = fmaf(v, wl[0], acc[q*4+0]);
            acc[q*4+1] = fmaf(v, wl[1], acc[q*4+1]);
            acc[q*4+2] = fmaf(v, wl[2], acc[q*4+2]);
            acc[q*4+3] = fmaf(v, wl[3], acc[q*4+3]);
        }
    }
    float* o = out + ((size_t)blockIdx.x * 256 + t) * 32;
#pragma unroll
    for (int q = 0; q < 8; ++q) {
        float ov[4];
#pragma unroll
        for (int j = 0; j < 4; ++j) {
            int c = q * 4 + j;
            float r = fmaxf(acc[c] + sB[c], 0.0f);
            ov[j] = fmaf(r, sS[c], sBi[c]);
        }
        *(float4*)&o[q * 4] = *(float4*)ov;
    }
}

// ======== conv2 as per-tap GEMM: [B,16,16,32] -> [B,8,8,64] ==================
// (round-11 form: m-minor A, two float4 broadcasts per ci.)
__global__ __launch_bounds__(256) void k_c2g(
    const float* __restrict__ in, const float* __restrict__ w,
    const float* __restrict__ bias,
    const float* __restrict__ g, const float* __restrict__ be,
    const float* __restrict__ mm, const float* __restrict__ vv,
    float* __restrict__ out)
{
    __shared__ __align__(16) float sA[32 * 132];
    __shared__ __align__(16) float sW[32 * 64];
    __shared__ __align__(16) float sB[64], sS[64], sBi[64];
    int t = threadIdx.x;
    int img0 = blockIdx.x * 2;
    if (t < 64) {
        float sc = bn_fold_scale(g[t], vv[t]);
        sS[t] = sc; sBi[t] = be[t] - mm[t] * sc; sB[t] = bias[t];
    }
    const float* in0 = in + (size_t)img0 * 8192;
    int tx = t & 15, ty = t >> 4;
    float acc[8][4];
#pragma unroll
    for (int i = 0; i < 8; ++i)
#pragma unroll
        for (int j = 0; j < 4; ++j) acc[i][j] = 0.0f;

    for (int tap = 0; tap < 25; ++tap) {
        int kh = tap / 5, kw = tap - kh * 5;
        __syncthreads();
        for (int i = t; i < 4096; i += 256) {
            int ci = i & 31, m = i >> 5;
            int im = m >> 6, pix = m & 63;
            int oy = pix >> 3, ox = pix & 7;
            int iy = 2 * oy - 1 + kh, ix = 2 * ox - 1 + kw;
            float v = ((unsigned)iy < 16u && (unsigned)ix < 16u)
                          ? in0[((size_t)im * 256 + iy * 16 + ix) * 32 + ci] : 0.0f;
            sA[ci * 132 + m] = v;
        }
        for (int i = t; i < 2048; i += 256) {
            int co = i & 63, ci = i >> 6;
            sW[ci * 64 + co] = w[((size_t)tap * 32 + ci) * 64 + co];
        }
        __syncthreads();
#pragma unroll 4
        for (int ci = 0; ci < 32; ++ci) {
            float b[4];
            *(float4*)b = *(const float4*)&sW[ci * 64 + tx * 4];
            float a0[4], a1[4];
            *(float4*)a0 = *(const float4*)&sA[ci * 132 + ty * 8];
            *(float4*)a1 = *(const float4*)&sA[ci * 132 + ty * 8 + 4];
#pragma unroll
            for (int mi = 0; mi < 4; ++mi)
#pragma unroll
                for (int j = 0; j < 4; ++j) {
                    acc[mi][j]     = fmaf(a0[mi], b[j], acc[mi][j]);
                    acc[4 + mi][j] = fmaf(a1[mi], b[j], acc[4 + mi][j]);
                }
        }
    }
    int c0 = tx * 4;
    float sc[4], bi[4], bv[4];
#pragma unroll
    for (int j = 0; j < 4; ++j) { sc[j] = sS[c0 + j]; bi[j] = sBi[c0 + j]; bv[j] = sB[c0 + j]; }
#pragma unroll
    for (int mi = 0; mi < 8; ++mi) {
        int m = ty * 8 + mi;
        int im = m >> 6, pix = m & 63;
        float ov[4];
#pragma unroll
        for (int j = 0; j < 4; ++j) {
            float r = fmaxf(acc[mi][j] + bv[j], 0.0f);
            ov[j] = fmaf(r, sc[j], bi[j]);
        }
        *(float4*)&out[((size_t)(img0 + im) * 64 + pix) * 64 + c0] = *(float4*)ov;
    }
}

// ======== conv3 per-tap GEMM + register double-buffer: [B,8,8,64]->[B,4,4,128]
// Round-12 blocking (4 img, N=128) + T14-style prefetch: tap+1's A/W tiles are
// loaded into registers DURING tap's compute, then ds_written after the
// barrier. Hides global-load latency that kept VALUBusy at 29%.
__global__ __launch_bounds__(256) void k_c3g(
    const float* __restrict__ in, const float* __restrict__ w,
    const float* __restrict__ bias,
    const float* __restrict__ g, const float* __restrict__ be,
    const float* __restrict__ mm, const float* __restrict__ vv,
    float* __restrict__ out)
{
    __shared__ __align__(16) float sA[64 * 68];    // [ci][m], stride 68
    __shared__ __align__(16) float sW[64 * 128];   // [ci][co]
    __shared__ __align__(16) float sB[128], sS[128], sBi[128];
    int t = threadIdx.x;
    int img0 = blockIdx.x * 4;
    if (t < 128) {
        float sc = bn_fold_scale(g[t], vv[t]);
        sS[t] = sc; sBi[t] = be[t] - mm[t] * sc; sB[t] = bias[t];
    }
    const float* in0 = in + (size_t)img0 * 4096;
    int tx = t & 15, ty = t >> 4;
    float acc[4][8];
#pragma unroll
    for (int i = 0; i < 4; ++i)
#pragma unroll
        for (int j = 0; j < 8; ++j) acc[i][j] = 0.0f;

    float aReg[16], wReg[32];
    // prologue: load tap 0 tiles into registers
    {
        int kh = 0, kw = 0;
#pragma unroll
        for (int r = 0; r < 16; ++r) {
            int i = t + r * 256;
            int ci = i & 63, m = i >> 6;
            int im = m >> 4, pix = m & 15;
            int oy = pix >> 2, ox = pix & 3;
            int iy = 2 * oy - 1 + kh, ix = 2 * ox - 1 + kw;
            aReg[r] = ((unsigned)iy < 8u && (unsigned)ix < 8u)
                          ? in0[((size_t)im * 64 + iy * 8 + ix) * 64 + ci] : 0.0f;
        }
#pragma unroll
        for (int r = 0; r < 32; ++r) {
            int i = t + r * 256;
            int co = i & 127, ci = i >> 7;
            wReg[r] = w[(size_t)ci * 128 + co];
        }
    }

    for (int tap = 0; tap < 25; ++tap) {
        __syncthreads();   // previous compute done reading LDS
        // commit registers to LDS
#pragma unroll
        for (int r = 0; r < 16; ++r) {
            int i = t + r * 256;
            int ci = i & 63, m = i >> 6;
            sA[ci * 68 + m] = aReg[r];
        }
#pragma unroll
        for (int r = 0; r < 32; ++r) {
            int i = t + r * 256;
            int co = i & 127, ci = i >> 7;
            sW[ci * 128 + co] = wReg[r];
        }
        // prefetch tap+1 (latency overlaps compute below)
        if (tap + 1 < 25) {
            int nt = tap + 1;
            int kh = nt / 5, kw = nt - kh * 5;
#pragma unroll
            for (int r = 0; r < 16; ++r) {
                int i = t + r * 256;
                int ci = i & 63, m = i >> 6;
                int im = m >> 4, pix = m & 15;
                int oy = pix >> 2, ox = pix & 3;
                int iy = 2 * oy - 1 + kh, ix = 2 * ox - 1 + kw;
                aReg[r] = ((unsigned)iy < 8u && (unsigned)ix < 8u)
                              ? in0[((size_t)im * 64 + iy * 8 + ix) * 64 + ci] : 0.0f;
            }
#pragma unroll
            for (int r = 0; r < 32; ++r) {
                int i = t + r * 256;
                int co = i & 127, ci = i >> 7;
                wReg[r] = w[((size_t)nt * 64 + ci) * 128 + co];
            }
        }
        __syncthreads();
#pragma unroll 2
        for (int ci = 0; ci < 64; ++ci) {
            float b[8];
            *(float4*)&b[0] = *(const float4*)&sW[ci * 128 + tx * 4];
            *(float4*)&b[4] = *(const float4*)&sW[ci * 128 + 64 + tx * 4];
            float a[4];
            *(float4*)a = *(const float4*)&sA[ci * 68 + ty * 4];
#pragma unroll
            for (int mi = 0; mi < 4; ++mi)
#pragma unroll
                for (int j = 0; j < 8; ++j)
                    acc[mi][j] = fmaf(a[mi], b[j], acc[mi][j]);
        }
    }
    int cA = tx * 4, cB = 64 + tx * 4;
#pragma unroll
    for (int mi = 0; mi < 4; ++mi) {
        int m = ty * 4 + mi;
        int im = m >> 4, pix = m & 15;
        float* o = &out[((size_t)(img0 + im) * 16 + pix) * 128];
        float ov0[4], ov1[4];
#pragma unroll
        for (int j = 0; j < 4; ++j) {
            float r = fmaxf(acc[mi][j] + sB[cA + j], 0.0f);
            ov0[j] = fmaf(r, sS[cA + j], sBi[cA + j]);
        }
#pragma unroll
        for (int j = 0; j < 4; ++j) {
            float r = fmaxf(acc[mi][4 + j] + sB[cB + j], 0.0f);
            ov1[j] = fmaf(r, sS[cB + j], sBi[cB + j]);
        }
        *(float4*)&o[cA] = *(float4*)ov0;
        *(float4*)&o[cB] = *(float4*)ov1;
    }
}

// ---------------- z partial GEMM: h3[Bc,2048] @ [wm|wv][2048,128] k-sliced ----
__global__ __launch_bounds__(256) void k_zpart(
    const float* __restrict__ A, const float* __restrict__ Wm,
    const float* __restrict__ Wv, float* __restrict__ part)
{
    __shared__ __align__(16) float sA[16 * 33];
    __shared__ __align__(16) float sW[32 * 256];
    int t = threadIdx.x;
    int img0 = blockIdx.x * 16;
    int k00 = blockIdx.y * 256;
    int li = t >> 4, cg = t & 15;
    float acc[16];
#pragma unroll
    for (int i = 0; i < 16; ++i) acc[i] = 0.0f;
    for (int k0 = 0; k0 < 256; k0 += 32) {
        for (int i = t; i < 512; i += 256) {
            int r = i >> 5, k = i & 31;
            sA[r * 33 + k] = A[(size_t)(img0 + r) * 2048 + k00 + k0 + k];
        }
        for (int i = t; i < 8192; i += 256) {
            int k = i >> 8, c = i & 255;
            float v = (c < 128) ? Wm[(size_t)(k00 + k0 + k) * 128 + c]
                                : Wv[(size_t)(k00 + k0 + k) * 128 + (c - 128)];
            sW[k * 256 + c] = v;
        }
        __syncthreads();
#pragma unroll 4
        for (int k = 0; k < 32; ++k) {
            float a = sA[li * 33 + k];
            const float* wr = &sW[k * 256];
#pragma unroll
            for (int q = 0; q < 4; ++q) {
                float wl[4];
                *(float4*)wl = *(const float4*)&wr[q * 64 + cg * 4];
                acc[q*4+0] = fmaf(a, wl[0], acc[q*4+0]);
                acc[q*4+1] = fmaf(a, wl[1], acc[q*4+1]);
                acc[q*4+2] = fmaf(a, wl[2], acc[q*4+2]);
                acc[q*4+3] = fmaf(a, wl[3], acc[q*4+3]);
            }
        }
        __syncthreads();
    }
    float* p = part + ((size_t)(img0 + li) * 8 + blockIdx.y) * 256;
#pragma unroll
    for (int q = 0; q < 4; ++q) {
        float4 v = make_float4(acc[q*4], acc[q*4+1], acc[q*4+2], acc[q*4+3]);
        *(float4*)&p[q * 64 + cg * 4] = v;
    }
}

// ---------------- z combine ----------------
__global__ __launch_bounds__(256) void k_zcombine(
    const float* __restrict__ part, const float* __restrict__ bm,
    const float* __restrict__ bv, const float* __restrict__ eps,
    float* __restrict__ z, int b0)
{
    int idx = blockIdx.x * 256 + threadIdx.x;
    int img = idx >> 7, c = idx & 127;
    const float* p = part + (size_t)img * 2048;
    float sm = 0.f, sv = 0.f;
#pragma unroll
    for (int s = 0; s < 8; ++s) { sm += p[s * 256 + c]; sv += p[s * 256 + 128 + c]; }
    float zm = fmaxf(sm + bm[c], 0.0f);
    float zlv = fmaxf(sv + bv[c], 0.0f);
    z[idx] = zm + expf(0.5f * zlv) * eps[(size_t)(b0 + img) * 128 + c];
}

// ---------------- generic K=128 GEMM: out = act(A[M,128]@W[128,N]+b), opt BN --
__global__ __launch_bounds__(256) void k_gemm128(
    const float* __restrict__ A, const float* __restrict__ W,
    const float* __restrict__ bias,
    const float* __restrict__ g, const float* __restrict__ be,
    const float* __restrict__ mm, const float* __restrict__ vv,
    float* __restrict__ out, int N, int M)
{
    __shared__ __align__(16) float sAt[64 * 68];
    __shared__ __align__(16) float sB[64 * 68];
    int t = threadIdx.x;
    int tx = t & 15, ty = t >> 4;
    int row0 = blockIdx.x * 64, col0 = blockIdx.y * 64;
    float acc[16];
#pragma unroll
    for (int i = 0; i < 16; ++i) acc[i] = 0.0f;
    for (int kc = 0; kc < 128; kc += 64) {
        for (int i = t; i < 4096; i += 256) {
            int r = i >> 6, k = i & 63;
            sAt[k * 68 + r] = (row0 + r < M) ? A[(size_t)(row0 + r) * 128 + kc + k] : 0.0f;
        }
        for (int i = t; i < 4096; i += 256) {
            int k = i >> 6, c = i & 63;
            sB[k * 68 + c] = W[(size_t)(kc + k) * N + col0 + c];
        }
        __syncthreads();
#pragma unroll 8
        for (int k = 0; k < 64; ++k) {
            float a[4], b[4];
            *(float4*)a = *(const float4*)&sAt[k * 68 + ty * 4];
            *(float4*)b = *(const float4*)&sB[k * 68 + tx * 4];
#pragma unroll
            for (int i = 0; i < 4; ++i)
#pragma unroll
                for (int j = 0; j < 4; ++j)
                    acc[i * 4 + j] = fmaf(a[i], b[j], acc[i * 4 + j]);
        }
        __syncthreads();
    }
    int c0 = col0 + tx * 4;
    float bvv[4];
    *(float4*)bvv = *(const float4*)&bias[c0];
    float sc[4], bi[4];
    bool has_bn = (g != nullptr);
    if (has_bn) {
#pragma unroll
        for (int j = 0; j < 4; ++j) {
            float s = bn_fold_scale(g[c0 + j], vv[c0 + j]);
            sc[j] = s; bi[j] = be[c0 + j] - mm[c0 + j] * s;
        }
    }
#pragma unroll
    for (int i = 0; i < 4; ++i) {
        int row = row0 + ty * 4 + i;
        if (row >= M) continue;
        float ov[4];
#pragma unroll
        for (int j = 0; j < 4; ++j) {
            float r = fmaxf(acc[i * 4 + j] + bvv[j], 0.0f);
            ov[j] = has_bn ? fmaf(r, sc[j], bi[j]) : r;
        }
        *(float4*)&out[(size_t)row * N + c0] = *(float4*)ov;
    }
}

// ====== convT2 img-pair fused: [B,8,8,128] -> [B,16,16,64], 4 img/block ======
template <int RY, int RX>
__device__ __forceinline__ void ct2g_body(
    const float* __restrict__ in0, const float* __restrict__ w,
    float* __restrict__ sA, float* __restrict__ sW,
    const float* __restrict__ sB, const float* __restrict__ sS,
    const float* __restrict__ sBi, float* __restrict__ out0)
{
    constexpr int NTY = RY ? 1 : 2;
    constexpr int NTX = RX ? 1 : 2;
    constexpr int TT = NTY * NTX;
    int t = threadIdx.x;
    int px0 = (t & 1) * 4;
    int py  = (t >> 1) & 7;
    int u   = (t >> 4) & 1;
    int ty  = t >> 5;            // 8 co-groups of 8
    int co0 = ty * 8;
    int imgA = 2 * u, imgB = 2 * u + 1;
    float acc0[4][8], acc1[4][8];
#pragma unroll
    for (int i = 0; i < 4; ++i)
#pragma unroll
        for (int j = 0; j < 8; ++j) { acc0[i][j] = 0.0f; acc1[i][j] = 0.0f; }

    for (int pass = 0; pass < 8; ++pass) {
        int ci0 = pass * 16;
        __syncthreads();
        for (int img = 0; img < 4; ++img) {
            const float* xin = in0 + (size_t)img * 8192;
            for (int i = t; i < 16 * 81; i += 256) {
                int ci = i & 15, pix = i >> 4;
                int r = pix / 9, c = pix - r * 9;
                int iy = r - 1, ix = c - 1;
                float v = (iy >= 0 && ix >= 0) ? xin[(iy * 8 + ix) * 128 + ci0 + ci] : 0.0f;
                sA[(img * 16 + ci) * 81 + pix] = v;
            }
        }
        for (int tb = 0; tb < TT; tb += 2) {
            if (tb) __syncthreads();
            for (int i = t; i < 2 * 16 * 64; i += 256) {
                int kk = i >> 6, co = i & 63;
                int tl = kk >> 4, ci = kk & 15;
                int tt = tb + tl; if (tt >= TT) tt = TT - 1;
                int kh = RY ? 1 : 2 * (tt / NTX);
                int kw = RX ? 1 : 2 * (tt % NTX);
                sW[kk * 64 + co] = w[((size_t)(kh * 3 + kw) * 128 + ci0 + ci) * 64 + co];
            }
            __syncthreads();
#pragma unroll
            for (int tl = 0; tl < 2; ++tl) {
                int tt = tb + tl;
                if (tt >= TT) break;
                int tY = tt / NTX, tX = tt % NTX;
                int r = RY ? (py + 1) : (py + tY);
                int cb = RX ? (px0 + 1) : (px0 + tX);
                int aB = r * 9 + cb;
#pragma unroll 4
                for (int ci = 0; ci < 16; ++ci) {
                    float b[8];
                    *(float4*)&b[0] = *(const float4*)&sW[(tl * 16 + ci) * 64 + co0];
                    *(float4*)&b[4] = *(const float4*)&sW[(tl * 16 + ci) * 64 + co0 + 4];
                    float a0[4], a1[4];
                    const float* pA = &sA[(imgA * 16 + ci) * 81 + aB];
                    const float* pB = &sA[(imgB * 16 + ci) * 81 + aB];
                    a0[0] = pA[0]; a0[1] = pA[1]; a0[2] = pA[2]; a0[3] = pA[3];
                    a1[0] = pB[0]; a1[1] = pB[1]; a1[2] = pB[2]; a1[3] = pB[3];
#pragma unroll
                    for (int i = 0; i < 4; ++i)
#pragma unroll
                        for (int j = 0; j < 8; ++j) {
                            acc0[i][j] = fmaf(a0[i], b[j], acc0[i][j]);
                            acc1[i][j] = fmaf(a1[i], b[j], acc1[i][j]);
                        }
                }
            }
        }
    }
#pragma unroll
    for (int l = 0; l < 2; ++l) {
        int img = 2 * u + l;
        float* oimg = out0 + (size_t)img * 16384;
#pragma unroll
        for (int i = 0; i < 4; ++i) {
            int oy = 2 * py + RY, ox = 2 * (px0 + i) + RX;
            float* o = oimg + (oy * 16 + ox) * 64 + co0;
            float ov0[4], ov1[4];
#pragma unroll
            for (int j = 0; j < 4; ++j) {
                int c = co0 + j;
                float r = fmaxf((l ? acc1[i][j] : acc0[i][j]) + sB[c], 0.0f);
                ov0[j] = fmaf(r, sS[c], sBi[c]);
            }
#pragma unroll
            for (int j = 0; j < 4; ++j) {
                int c = co0 + 4 + j;
                float r = fmaxf((l ? acc1[i][4 + j] : acc0[i][4 + j]) + sB[c], 0.0f);
                ov1[j] = fmaf(r, sS[c], sBi[c]);
            }
            *(float4*)o = *(float4*)ov0;
            *(float4*)(o + 4) = *(float4*)ov1;
        }
    }
}

__global__ __launch_bounds__(256, 4) void k_ct2g(
    const float* __restrict__ in, const float* __restrict__ w,
    const float* __restrict__ bias,
    const float* __restrict__ g, const float* __restrict__ be,
    const float* __restrict__ mm, const float* __restrict__ vv,
    float* __restrict__ out)
{
    __shared__ __align__(16) float sA[4 * 16 * 81];
    __shared__ __align__(16) float sW[2 * 16 * 64];
    __shared__ __align__(16) float sB[64], sS[64], sBi[64];
    int t = threadIdx.x;
    if (t < 64) {
        float sc = bn_fold_scale(g[t], vv[t]);
        sS[t] = sc; sBi[t] = be[t] - mm[t] * sc; sB[t] = bias[t];
    }
    const float* in0 = in + (size_t)blockIdx.x * 4 * 8192;
    float* out0 = out + (size_t)blockIdx.x * 4 * 16384;
    switch (blockIdx.y) {
        case 0:  ct2g_body<0,0>(in0, w, sA, sW, sB, sS, sBi, out0); break;
        case 1:  ct2g_body<0,1>(in0, w, sA, sW, sB, sS, sBi, out0); break;
        case 2:  ct2g_body<1,0>(in0, w, sA, sW, sB, sS, sBi, out0); break;
        default: ct2g_body<1,1>(in0, w, sA, sW, sB, sS, sBi, out0); break;
    }
}

// ====== convT3 img-pair fused: [B,16,16,64] -> [B,32,32,32], 2 img/block =====
template <int RY, int RX>
__device__ __forceinline__ void ct3g_body(
    const float* __restrict__ in0, const float* __restrict__ w,
    float* __restrict__ sA, float* __restrict__ sW,
    const float* __restrict__ sB, const float* __restrict__ sS,
    const float* __restrict__ sBi, float* __restrict__ out0)
{
    constexpr int NTY = RY ? 1 : 2;
    constexpr int NTX = RX ? 1 : 2;
    constexpr int TT = NTY * NTX;
    int t = threadIdx.x;
    int px0 = (t & 3) * 4;
    int py  = (t >> 2) & 15;
    int ty  = t >> 6;            // 4 co-groups of 8
    int co0 = ty * 8;
    float acc0[4][8], acc1[4][8];
#pragma unroll
    for (int i = 0; i < 4; ++i)
#pragma unroll
        for (int j = 0; j < 8; ++j) { acc0[i][j] = 0.0f; acc1[i][j] = 0.0f; }

    for (int pass = 0; pass < 8; ++pass) {
        int ci0 = pass * 8;
        __syncthreads();
        for (int img = 0; img < 2; ++img) {
            const float* xin = in0 + (size_t)img * 16384;
            for (int i = t; i < 8 * 289; i += 256) {
                int ci = i & 7, pix = i >> 3;
                int r = pix / 17, c = pix - r * 17;
                int iy = r - 1, ix = c - 1;
                float v = (iy >= 0 && ix >= 0) ? xin[(iy * 16 + ix) * 64 + ci0 + ci] : 0.0f;
                sA[(img * 8 + ci) * 289 + pix] = v;
            }
        }
        for (int tb = 0; tb < TT; tb += 2) {
            if (tb) __syncthreads();
            for (int i = t; i < 2 * 8 * 32; i += 256) {
                int kk = i >> 5, co = i & 31;
                int tl = kk >> 3, ci = kk & 7;
                int tt = tb + tl; if (tt >= TT) tt = TT - 1;
                int kh = RY ? 1 : 2 * (tt / NTX);
                int kw = RX ? 1 : 2 * (tt % NTX);
                sW[kk * 32 + co] = w[((size_t)(kh * 3 + kw) * 64 + ci0 + ci) * 32 + co];
            }
            __syncthreads();
#pragma unroll
            for (int tl = 0; tl < 2; ++tl) {
                int tt = tb + tl;
                if (tt >= TT) break;
                int tY = tt / NTX, tX = tt % NTX;
                int r = RY ? (py + 1) : (py + tY);
                int cb = RX ? (px0 + 1) : (px0 + tX);
                int aB = r * 17 + cb;
#pragma unroll 4
                for (int ci = 0; ci < 8; ++ci) {
                    float b[8];
                    *(float4*)&b[0] = *(const float4*)&sW[(tl * 8 + ci) * 32 + co0];
                    *(float4*)&b[4] = *(const float4*)&sW[(tl * 8 + ci) * 32 + co0 + 4];
                    float a0[4], a1[4];
                    const float* pA = &sA[ci * 289 + aB];
                    const float* pB = &sA[(8 + ci) * 289 + aB];
                    a0[0] = pA[0]; a0[1] = pA[1]; a0[2] = pA[2]; a0[3] = pA[3];
                    a1[0] = pB[0]; a1[1] = pB[1]; a1[2] = pB[2]; a1[3] = pB[3];
#pragma unroll
                    for (int i = 0; i < 4; ++i)
#pragma unroll
                        for (int j = 0; j < 8; ++j) {
                            acc0[i][j] = fmaf(a0[i], b[j], acc0[i][j]);
                            acc1[i][j] = fmaf(a1[i], b[j], acc1[i][j]);
                        }
                }
            }
        }
    }
#pragma unroll
    for (int l = 0; l < 2; ++l) {
        float* oimg = out0 + (size_t)l * 32768;
#pragma unroll
        for (int i = 0; i < 4; ++i) {
            int oy = 2 * py + RY, ox = 2 * (px0 + i) + RX;
            float* o = oimg + (oy * 32 + ox) * 32 + co0;
            float ov0[4], ov1[4];
#pragma unroll
            for (int j = 0; j < 4; ++j) {
                int c = co0 + j;
                float r = fmaxf((l ? acc1[i][j] : acc0[i][j]) + sB[c], 0.0f);
                ov0[j] = fmaf(r, sS[c], sBi[c]);
            }
#pragma unroll
            for (int j = 0; j < 4; ++j) {
                int c = co0 + 4 + j;
                float r = fmaxf((l ? acc1[i][4 + j] : acc0[i][4 + j]) + sB[c], 0.0f);
                ov1[j] = fmaf(r, sS[c], sBi[c]);
            }
            *(float4*)o = *(float4*)ov0;
            *(float4*)(o + 4) = *(float4*)ov1;
        }
    }
}

__global__ __launch_bounds__(256, 4) void k_ct3g(
    const float* __restrict__ in, const float* __restrict__ w,
    const float* __restrict__ bias,
    const float* __restrict__ g, const float* __restrict__ be,
    const float* __restrict__ mm, const float* __restrict__ vv,
    float* __restrict__ out)
{
    __shared__ __align__(16) float sA[2 * 8 * 289];
    __shared__ __align__(16) float sW[2 * 8 * 32];
    __shared__ __align__(16) float sB[32], sS[32], sBi[32];
    int t = threadIdx.x;
    if (t < 32) {
        float sc = bn_fold_scale(g[t], vv[t]);
        sS[t] = sc; sBi[t] = be[t] - mm[t] * sc; sB[t] = bias[t];
    }
    const float* in0 = in + (size_t)blockIdx.x * 2 * 16384;
    float* out0 = out + (size_t)blockIdx.x * 2 * 32768;
    switch (blockIdx.y) {
        case 0:  ct3g_body<0,0>(in0, w, sA, sW, sB, sS, sBi, out0); break;
        case 1:  ct3g_body<0,1>(in0, w, sA, sW, sB, sS, sBi, out0); break;
        case 2:  ct3g_body<1,0>(in0, w, sA, sW, sB, sS, sBi, out0); break;
        default: ct3g_body<1,1>(in0, w, sA, sW, sB, sS, sBi, out0); break;
    }
}

// ---------------- convT4 + sigmoid + error: [B,32,32,32] -> err [Bc,32,32] ----
__global__ __launch_bounds__(256) void k_convT4_err(
    const float* __restrict__ in, const float* __restrict__ w,
    const float* __restrict__ b, const float* __restrict__ x,
    float* __restrict__ err, int b0)
{
    __shared__ __align__(16) float sIn[32 * 342];
    int t = threadIdx.x;
    int quart = blockIdx.x, img = blockIdx.y;
    int r0 = quart * 8;
    const float* xin = in + (size_t)img * 32768;
    for (int i = t; i < 10880; i += 256) {
        int pix = i >> 5, ci = i & 31;
        int lr = pix / 34;
        int cx = pix - lr * 34 - 1;
        int gy = r0 - 1 + lr;
        float v = (((unsigned)gy < 32u) && ((unsigned)cx < 32u))
                      ? xin[(gy * 32 + cx) * 32 + ci] : 0.0f;
        sIn[ci * 342 + pix] = v;
    }
    __syncthreads();
    int ly = t >> 5, lx = t & 31;
    float a0 = 0.f, a1 = 0.f, a2 = 0.f;
#pragma unroll
    for (int kh = 0; kh < 3; ++kh)
#pragma unroll
        for (int kw = 0; kw < 3; ++kw) {
            int pix = (ly + kh) * 34 + (lx + kw);
            const float* wp = w + ((kh * 3 + kw) * 32) * 3;
#pragma unroll 4
            for (int ci = 0; ci < 32; ++ci) {
                float v = sIn[ci * 342 + pix];
                a0 = fmaf(v, wp[ci * 3 + 0], a0);
                a1 = fmaf(v, wp[ci * 3 + 1], a1);
                a2 = fmaf(v, wp[ci * 3 + 2], a2);
            }
        }
    float s0 = 1.0f / (1.0f + expf(-(a0 + b[0])));
    float s1 = 1.0f / (1.0f + expf(-(a1 + b[1])));
    float s2 = 1.0f / (1.0f + expf(-(a2 + b[2])));
    int oy = r0 + ly;
    size_t xi = (((size_t)(b0 + img) * 32 + oy) * 32 + lx) * 3;
    float d0 = x[xi + 0] - s0;
    float d1 = x[xi + 1] - s1;
    float d2 = x[xi + 2] - s2;
    err[(size_t)img * 1024 + oy * 32 + lx] = (d0 * d0 + d1 * d1 + d2 * d2) * (1.0f / 3.0f);
}

// ---------------- Otsu + mask (per-chunk) ----------------
__global__ __launch_bounds__(256) void k_otsu(
    const float* __restrict__ err, int* __restrict__ mask)
{
    __shared__ float sE[1024];
    __shared__ float sRed[4];
    __shared__ float sSig[96];
    __shared__ float sThr;
    int img = blockIdx.x, t = threadIdx.x;
    const float* e = err + (size_t)img * 1024;
    float part = 0.f;
    for (int i = t; i < 1024; i += 256) { float v = e[i]; sE[i] = v; part += v; }
    for (int o = 32; o; o >>= 1) part += __shfl_down(part, o);
    if ((t & 63) == 0) sRed[t >> 6] = part;
    __syncthreads();
    float tot = sRed[0] + sRed[1] + sRed[2] + sRed[3];
    if (t < 91) {
        float T = (float)((double)t * 0.01);
        int c = 0; float s = 0.f;
        for (int i = 0; i < 1024; ++i) {
            float v = sE[i];
            bool lt = v < T;
            c += lt ? 1 : 0;
            s += lt ? v : 0.0f;
        }
        float cf = (float)c;
        float p0 = cf * (1.0f / 1024.0f);
        float p1 = 1.0f - p0;
        float m0 = s / fmaxf(cf, 1.0f);
        float m1 = (tot - s) / fmaxf(1024.0f - cf, 1.0f);
        float d = m0 - m1;
        sSig[t] = (c > 0 && c < 1024) ? (p0 * p1) * (d * d) : 0.0f;
    }
    __syncthreads();
    if (t == 0) {
        float best = sSig[0]; int bk = 0;
        for (int k = 1; k < 91; ++k)
            if (sSig[k] > best) { best = sSig[k]; bk = k; }
        sThr = (float)((double)bk * 0.01);
    }
    __syncthreads();
    float thr = sThr;
    int* m = mask + (size_t)img * 1024;
    for (int i = t; i < 1024; i += 256) m[i] = (sE[i] < thr) ? 1 : 0;
}

// ---------------- launch ----------------
extern "C" void kernel_launch(void* const* d_in, const int* in_sizes, int n_in,
                              void* d_out, int out_size, void* d_ws, size_t ws_size,
                              hipStream_t stream)
{
    (void)in_sizes; (void)out_size;
    const float* p[46];
    bool flat = (n_in >= 46);
    if (flat) {
        for (int i = 0; i < 46; ++i) p[i] = (const float*)d_in[i];
    } else {
        int o = 0;
        int s = 0;
        auto leaf = [&](int count) {
            for (int j = 0; j < count; ++j) p[o++] = (const float*)d_in[s++];
        };
        auto bn4 = [&](int C) {
            const float* base = (const float*)d_in[s++];
            p[o++] = base; p[o++] = base + C; p[o++] = base + 2 * C; p[o++] = base + 3 * C;
        };
        leaf(2);            // x, eps_z
        leaf(2); bn4(32);   // e_w1, e_b1, e_bn1
        leaf(2); bn4(64);   // e_w2, e_b2, e_bn2
        leaf(2); bn4(128);  // e_w3, e_b3, e_bn3
        leaf(4);            // e_wm, e_bm, e_wv, e_bv
        leaf(2);            // d_wd, d_bd
        leaf(2); bn4(128);  // d_w1, d_b1, d_bn1
        leaf(2); bn4(64);   // d_w2, d_b2, d_bn2
        leaf(2); bn4(32);   // d_w3, d_b3, d_bn3
        leaf(2);            // d_w4, d_b4
    }
    const float* x      = p[0];
    const float* epsz   = p[1];
    const float* e_w1   = p[2];
    const float* e_b1   = p[3];
    const float* e_bn1g = p[4], *e_bn1b = p[5], *e_bn1m = p[6], *e_bn1v = p[7];
    const float* e_w2   = p[8];
    const float* e_b2   = p[9];
    const float* e_bn2g = p[10], *e_bn2b = p[11], *e_bn2m = p[12], *e_bn2v = p[13];
    const float* e_w3   = p[14];
    const float* e_b3   = p[15];
    const float* e_bn3g = p[16], *e_bn3b = p[17], *e_bn3m = p[18], *e_bn3v = p[19];
    const float* e_wm   = p[20];
    const float* e_bm   = p[21];
    const float* e_wv   = p[22];
    const float* e_bv   = p[23];
    const float* d_wd   = p[24];
    const float* d_bd   = p[25];
    const float* d_w1   = p[26];
    const float* d_b1   = p[27];
    const float* d_bn1g = p[28], *d_bn1b = p[29], *d_bn1m = p[30], *d_bn1v = p[31];
    const float* d_w2   = p[32];
    const float* d_b2   = p[33];
    const float* d_bn2g = p[34], *d_bn2b = p[35], *d_bn2m = p[36], *d_bn2v = p[37];
    const float* d_w3   = p[38];
    const float* d_b3   = p[39];
    const float* d_bn3g = p[40], *d_bn3b = p[41], *d_bn3m = p[42], *d_bn3v = p[43];
    const float* d_w4   = p[44];
    const float* d_b4   = p[45];
    int* mask = (int*)d_out;

    float* ws = (float*)d_ws;
    int Bc = B_TOTAL;
    while (Bc > 16) {
        size_t need = (size_t)Bc * 50304u * 4u;
        if (need <= ws_size) break;
        Bc >>= 1;
    }
    float* err = ws;
    float* z   = err + (size_t)Bc * 1024;
    float* P   = z + (size_t)Bc * 128;
    float* Q   = P + (size_t)Bc * 16384;

    for (int b0 = 0; b0 < B_TOTAL; b0 += Bc) {
        k_conv1<<<Bc, 256, 0, stream>>>(x, e_w1, e_b1, e_bn1g, e_bn1b, e_bn1m, e_bn1v, P, b0);
        k_c2g<<<Bc / 2, 256, 0, stream>>>(P, e_w2, e_b2, e_bn2g, e_bn2b, e_bn2m, e_bn2v, Q);
        k_c3g<<<Bc / 4, 256, 0, stream>>>(Q, e_w3, e_b3, e_bn3g, e_bn3b, e_bn3m, e_bn3v, P);
        k_zpart<<<dim3(Bc / 16, 8), 256, 0, stream>>>(P, e_wm, e_wv, Q);
        k_zcombine<<<(Bc * 128) / 256, 256, 0, stream>>>(Q, e_bm, e_bv, epsz, z, b0);
        k_gemm128<<<dim3((Bc + 63) / 64, 128), 256, 0, stream>>>(z, d_wd, d_bd,
            nullptr, nullptr, nullptr, nullptr, P, 8192, Bc);
        k_gemm128<<<dim3(Bc, 2), 256, 0, stream>>>(P, d_w1, d_b1,
            d_bn1g, d_bn1b, d_bn1m, d_bn1v, Q, 128, Bc * 64);
        k_ct2g<<<dim3(Bc / 4, 4), 256, 0, stream>>>(Q, d_w2, d_b2, d_bn2g, d_bn2b, d_bn2m, d_bn2v, P);
        k_ct3g<<<dim3(Bc / 2, 4), 256, 0, stream>>>(P, d_w3, d_b3, d_bn3g, d_bn3b, d_bn3m, d_bn3v, Q);
        k_convT4_err<<<dim3(4, Bc), 256, 0, stream>>>(Q, d_w4, d_b4, x, err, b0);
        k_otsu<<<Bc, 256, 0, stream>>>(err, mask + (size_t)b0 * 1024);
    }
}

// Round 15
// 1961.421 us; speedup vs baseline: 1.2673x; 1.0711x over previous
//
#include <hip/hip_runtime.h>
#include <math.h>

#define B_TOTAL 2048

// ---------------- helpers ----------------

__device__ __forceinline__ float bn_fold_scale(float g, float v) {
    return g * (float)(1.0 / sqrt((double)v + 1e-3));
}

// ---------------- conv1: [B,32,32,3] -> [B,16,16,32], 5x5 s2 SAME, relu+BN ----
__global__ __launch_bounds__(256) void k_conv1(
    const float* __restrict__ x, const float* __restrict__ w,
    const float* __restrict__ bias,
    const float* __restrict__ g, const float* __restrict__ be,
    const float* __restrict__ mm, const float* __restrict__ vv,
    float* __restrict__ out, int b0)
{
    __shared__ __align__(16) float sIn[3072];
    __shared__ __align__(16) float sW[2400];
    __shared__ __align__(16) float sB[32], sS[32], sBi[32];
    int t = threadIdx.x;
    const float* xin = x + (size_t)(b0 + blockIdx.x) * 3072;
    for (int i = t; i < 3072; i += 256) sIn[i] = xin[i];
    for (int i = t; i < 2400; i += 256) sW[i] = w[i];
    if (t < 32) {
        float sc = bn_fold_scale(g[t], vv[t]);
        sS[t] = sc; sBi[t] = be[t] - mm[t] * sc; sB[t] = bias[t];
    }
    __syncthreads();
    int oy = t >> 4, ox = t & 15;
    float patch[75];
#pragma unroll
    for (int kh = 0; kh < 5; ++kh) {
        int iy = 2 * oy - 1 + kh;
#pragma unroll
        for (int kw = 0; kw < 5; ++kw) {
            int ix = 2 * ox - 1 + kw;
            bool v = ((unsigned)iy < 32u) && ((unsigned)ix < 32u);
            int base = (iy * 32 + ix) * 3;
#pragma unroll
            for (int c = 0; c < 3; ++c)
                patch[(kh * 5 + kw) * 3 + c] = v ? sIn[base + c] : 0.0f;
        }
    }
    float acc[32];
#pragma unroll
    for (int i = 0; i < 32; ++i) acc[i] = 0.0f;
#pragma unroll 5
    for (int i = 0; i < 75; ++i) {
        float v = patch[i];
        const float* wr = &sW[i * 32];
#pragma unroll
        for (int q = 0; q < 8; ++q) {
            float wl[4];
            *(float4*)wl = *(const float4*)&wr[q * 4];
            acc[q*4+0] = fmaf(v, wl[0], acc[q*4+0]);
            acc[q*4+1] = fmaf(v, wl[1], acc[q*4+1]);
            acc[q*4+2] = fmaf(v, wl[2], acc[q*4+2]);
            acc[q*4+3] = fmaf(v, wl[3], acc[q*4+3]);
        }
    }
    float* o = out + ((size_t)blockIdx.x * 256 + t) * 32;
#pragma unroll
    for (int q = 0; q < 8; ++q) {
        float ov[4];
#pragma unroll
        for (int j = 0; j < 4; ++j) {
            int c = q * 4 + j;
            float r = fmaxf(acc[c] + sB[c], 0.0f);
            ov[j] = fmaf(r, sS[c], sBi[c]);
        }
        *(float4*)&o[q * 4] = *(float4*)ov;
    }
}

// ======== conv2 per-tap GEMM + register double-buffer ========================
// [B,16,16,32] -> [B,8,8,64]. Block = 2 images. Per tap: commit regs->LDS,
// prefetch tap+1 into regs (latency hides under compute), compute.
__global__ __launch_bounds__(256) void k_c2g(
    const float* __restrict__ in, const float* __restrict__ w,
    const float* __restrict__ bias,
    const float* __restrict__ g, const float* __restrict__ be,
    const float* __restrict__ mm, const float* __restrict__ vv,
    float* __restrict__ out)
{
    __shared__ __align__(16) float sA[32 * 132];
    __shared__ __align__(16) float sW[32 * 64];
    __shared__ __align__(16) float sB[64], sS[64], sBi[64];
    int t = threadIdx.x;
    int img0 = blockIdx.x * 2;
    if (t < 64) {
        float sc = bn_fold_scale(g[t], vv[t]);
        sS[t] = sc; sBi[t] = be[t] - mm[t] * sc; sB[t] = bias[t];
    }
    const float* in0 = in + (size_t)img0 * 8192;
    int tx = t & 15, ty = t >> 4;
    float acc[8][4];
#pragma unroll
    for (int i = 0; i < 8; ++i)
#pragma unroll
        for (int j = 0; j < 4; ++j) acc[i][j] = 0.0f;

    float aReg[16], wReg[8];
    {
        int kh = 0, kw = 0;
#pragma unroll
        for (int r = 0; r < 16; ++r) {
            int i = t + r * 256;
            int ci = i & 31, m = i >> 5;
            int im = m >> 6, pix = m & 63;
            int oy = pix >> 3, ox = pix & 7;
            int iy = 2 * oy - 1 + kh, ix = 2 * ox - 1 + kw;
            aReg[r] = ((unsigned)iy < 16u && (unsigned)ix < 16u)
                          ? in0[((size_t)im * 256 + iy * 16 + ix) * 32 + ci] : 0.0f;
        }
#pragma unroll
        for (int r = 0; r < 8; ++r) {
            int i = t + r * 256;
            int co = i & 63, ci = i >> 6;
            wReg[r] = w[(size_t)ci * 64 + co];
        }
    }

    for (int tap = 0; tap < 25; ++tap) {
        __syncthreads();
#pragma unroll
        for (int r = 0; r < 16; ++r) {
            int i = t + r * 256;
            int ci = i & 31, m = i >> 5;
            sA[ci * 132 + m] = aReg[r];
        }
#pragma unroll
        for (int r = 0; r < 8; ++r) {
            int i = t + r * 256;
            int co = i & 63, ci = i >> 6;
            sW[ci * 64 + co] = wReg[r];
        }
        if (tap + 1 < 25) {
            int nt = tap + 1;
            int kh = nt / 5, kw = nt - kh * 5;
#pragma unroll
            for (int r = 0; r < 16; ++r) {
                int i = t + r * 256;
                int ci = i & 31, m = i >> 5;
                int im = m >> 6, pix = m & 63;
                int oy = pix >> 3, ox = pix & 7;
                int iy = 2 * oy - 1 + kh, ix = 2 * ox - 1 + kw;
                aReg[r] = ((unsigned)iy < 16u && (unsigned)ix < 16u)
                              ? in0[((size_t)im * 256 + iy * 16 + ix) * 32 + ci] : 0.0f;
            }
#pragma unroll
            for (int r = 0; r < 8; ++r) {
                int i = t + r * 256;
                int co = i & 63, ci = i >> 6;
                wReg[r] = w[((size_t)nt * 32 + ci) * 64 + co];
            }
        }
        __syncthreads();
#pragma unroll 4
        for (int ci = 0; ci < 32; ++ci) {
            float b[4];
            *(float4*)b = *(const float4*)&sW[ci * 64 + tx * 4];
            float a0[4], a1[4];
            *(float4*)a0 = *(const float4*)&sA[ci * 132 + ty * 8];
            *(float4*)a1 = *(const float4*)&sA[ci * 132 + ty * 8 + 4];
#pragma unroll
            for (int mi = 0; mi < 4; ++mi)
#pragma unroll
                for (int j = 0; j < 4; ++j) {
                    acc[mi][j]     = fmaf(a0[mi], b[j], acc[mi][j]);
                    acc[4 + mi][j] = fmaf(a1[mi], b[j], acc[4 + mi][j]);
                }
        }
    }
    int c0 = tx * 4;
    float sc[4], bi[4], bv[4];
#pragma unroll
    for (int j = 0; j < 4; ++j) { sc[j] = sS[c0 + j]; bi[j] = sBi[c0 + j]; bv[j] = sB[c0 + j]; }
#pragma unroll
    for (int mi = 0; mi < 8; ++mi) {
        int m = ty * 8 + mi;
        int im = m >> 6, pix = m & 63;
        float ov[4];
#pragma unroll
        for (int j = 0; j < 4; ++j) {
            float r = fmaxf(acc[mi][j] + bv[j], 0.0f);
            ov[j] = fmaf(r, sc[j], bi[j]);
        }
        *(float4*)&out[((size_t)(img0 + im) * 64 + pix) * 64 + c0] = *(float4*)ov;
    }
}

// ======== conv3 per-tap GEMM + register double-buffer (round-14, proven) =====
__global__ __launch_bounds__(256) void k_c3g(
    const float* __restrict__ in, const float* __restrict__ w,
    const float* __restrict__ bias,
    const float* __restrict__ g, const float* __restrict__ be,
    const float* __restrict__ mm, const float* __restrict__ vv,
    float* __restrict__ out)
{
    __shared__ __align__(16) float sA[64 * 68];
    __shared__ __align__(16) float sW[64 * 128];
    __shared__ __align__(16) float sB[128], sS[128], sBi[128];
    int t = threadIdx.x;
    int img0 = blockIdx.x * 4;
    if (t < 128) {
        float sc = bn_fold_scale(g[t], vv[t]);
        sS[t] = sc; sBi[t] = be[t] - mm[t] * sc; sB[t] = bias[t];
    }
    const float* in0 = in + (size_t)img0 * 4096;
    int tx = t & 15, ty = t >> 4;
    float acc[4][8];
#pragma unroll
    for (int i = 0; i < 4; ++i)
#pragma unroll
        for (int j = 0; j < 8; ++j) acc[i][j] = 0.0f;

    float aReg[16], wReg[32];
    {
        int kh = 0, kw = 0;
#pragma unroll
        for (int r = 0; r < 16; ++r) {
            int i = t + r * 256;
            int ci = i & 63, m = i >> 6;
            int im = m >> 4, pix = m & 15;
            int oy = pix >> 2, ox = pix & 3;
            int iy = 2 * oy - 1 + kh, ix = 2 * ox - 1 + kw;
            aReg[r] = ((unsigned)iy < 8u && (unsigned)ix < 8u)
                          ? in0[((size_t)im * 64 + iy * 8 + ix) * 64 + ci] : 0.0f;
        }
#pragma unroll
        for (int r = 0; r < 32; ++r) {
            int i = t + r * 256;
            int co = i & 127, ci = i >> 7;
            wReg[r] = w[(size_t)ci * 128 + co];
        }
    }

    for (int tap = 0; tap < 25; ++tap) {
        __syncthreads();
#pragma unroll
        for (int r = 0; r < 16; ++r) {
            int i = t + r * 256;
            int ci = i & 63, m = i >> 6;
            sA[ci * 68 + m] = aReg[r];
        }
#pragma unroll
        for (int r = 0; r < 32; ++r) {
            int i = t + r * 256;
            int co = i & 127, ci = i >> 7;
            sW[ci * 128 + co] = wReg[r];
        }
        if (tap + 1 < 25) {
            int nt = tap + 1;
            int kh = nt / 5, kw = nt - kh * 5;
#pragma unroll
            for (int r = 0; r < 16; ++r) {
                int i = t + r * 256;
                int ci = i & 63, m = i >> 6;
                int im = m >> 4, pix = m & 15;
                int oy = pix >> 2, ox = pix & 3;
                int iy = 2 * oy - 1 + kh, ix = 2 * ox - 1 + kw;
                aReg[r] = ((unsigned)iy < 8u && (unsigned)ix < 8u)
                              ? in0[((size_t)im * 64 + iy * 8 + ix) * 64 + ci] : 0.0f;
            }
#pragma unroll
            for (int r = 0; r < 32; ++r) {
                int i = t + r * 256;
                int co = i & 127, ci = i >> 7;
                wReg[r] = w[((size_t)nt * 64 + ci) * 128 + co];
            }
        }
        __syncthreads();
#pragma unroll 2
        for (int ci = 0; ci < 64; ++ci) {
            float b[8];
            *(float4*)&b[0] = *(const float4*)&sW[ci * 128 + tx * 4];
            *(float4*)&b[4] = *(const float4*)&sW[ci * 128 + 64 + tx * 4];
            float a[4];
            *(float4*)a = *(const float4*)&sA[ci * 68 + ty * 4];
#pragma unroll
            for (int mi = 0; mi < 4; ++mi)
#pragma unroll
                for (int j = 0; j < 8; ++j)
                    acc[mi][j] = fmaf(a[mi], b[j], acc[mi][j]);
        }
    }
    int cA = tx * 4, cB = 64 + tx * 4;
#pragma unroll
    for (int mi = 0; mi < 4; ++mi) {
        int m = ty * 4 + mi;
        int im = m >> 4, pix = m & 15;
        float* o = &out[((size_t)(img0 + im) * 16 + pix) * 128];
        float ov0[4], ov1[4];
#pragma unroll
        for (int j = 0; j < 4; ++j) {
            float r = fmaxf(acc[mi][j] + sB[cA + j], 0.0f);
            ov0[j] = fmaf(r, sS[cA + j], sBi[cA + j]);
        }
#pragma unroll
        for (int j = 0; j < 4; ++j) {
            float r = fmaxf(acc[mi][4 + j] + sB[cB + j], 0.0f);
            ov1[j] = fmaf(r, sS[cB + j], sBi[cB + j]);
        }
        *(float4*)&o[cA] = *(float4*)ov0;
        *(float4*)&o[cB] = *(float4*)ov1;
    }
}

// ---------------- z partial GEMM + register double-buffer --------------------
__global__ __launch_bounds__(256) void k_zpart(
    const float* __restrict__ A, const float* __restrict__ Wm,
    const float* __restrict__ Wv, float* __restrict__ part)
{
    __shared__ __align__(16) float sA[16 * 33];
    __shared__ __align__(16) float sW[32 * 256];
    int t = threadIdx.x;
    int img0 = blockIdx.x * 16;
    int k00 = blockIdx.y * 256;
    int li = t >> 4, cg = t & 15;
    float acc[16];
#pragma unroll
    for (int i = 0; i < 16; ++i) acc[i] = 0.0f;

    float aReg[2], wReg[32];
    {
#pragma unroll
        for (int r = 0; r < 2; ++r) {
            int i = t + r * 256;
            int rr = i >> 5, k = i & 31;
            aReg[r] = A[(size_t)(img0 + rr) * 2048 + k00 + k];
        }
#pragma unroll
        for (int r = 0; r < 32; ++r) {
            int i = t + r * 256;
            int k = i >> 8, c = i & 255;
            wReg[r] = (c < 128) ? Wm[(size_t)(k00 + k) * 128 + c]
                                : Wv[(size_t)(k00 + k) * 128 + (c - 128)];
        }
    }

    for (int k0 = 0; k0 < 256; k0 += 32) {
        __syncthreads();
#pragma unroll
        for (int r = 0; r < 2; ++r) {
            int i = t + r * 256;
            int rr = i >> 5, k = i & 31;
            sA[rr * 33 + k] = aReg[r];
        }
#pragma unroll
        for (int r = 0; r < 32; ++r) {
            int i = t + r * 256;
            int k = i >> 8, c = i & 255;
            sW[k * 256 + c] = wReg[r];
        }
        if (k0 + 32 < 256) {
            int nk = k00 + k0 + 32;
#pragma unroll
            for (int r = 0; r < 2; ++r) {
                int i = t + r * 256;
                int rr = i >> 5, k = i & 31;
                aReg[r] = A[(size_t)(img0 + rr) * 2048 + nk + k];
            }
#pragma unroll
            for (int r = 0; r < 32; ++r) {
                int i = t + r * 256;
                int k = i >> 8, c = i & 255;
                wReg[r] = (c < 128) ? Wm[(size_t)(nk + k) * 128 + c]
                                    : Wv[(size_t)(nk + k) * 128 + (c - 128)];
            }
        }
        __syncthreads();
#pragma unroll 4
        for (int k = 0; k < 32; ++k) {
            float a = sA[li * 33 + k];
            const float* wr = &sW[k * 256];
#pragma unroll
            for (int q = 0; q < 4; ++q) {
                float wl[4];
                *(float4*)wl = *(const float4*)&wr[q * 64 + cg * 4];
                acc[q*4+0] = fmaf(a, wl[0], acc[q*4+0]);
                acc[q*4+1] = fmaf(a, wl[1], acc[q*4+1]);
                acc[q*4+2] = fmaf(a, wl[2], acc[q*4+2]);
                acc[q*4+3] = fmaf(a, wl[3], acc[q*4+3]);
            }
        }
    }
    float* p = part + ((size_t)(img0 + li) * 8 + blockIdx.y) * 256;
#pragma unroll
    for (int q = 0; q < 4; ++q) {
        float4 v = make_float4(acc[q*4], acc[q*4+1], acc[q*4+2], acc[q*4+3]);
        *(float4*)&p[q * 64 + cg * 4] = v;
    }
}

// ---------------- z combine ----------------
__global__ __launch_bounds__(256) void k_zcombine(
    const float* __restrict__ part, const float* __restrict__ bm,
    const float* __restrict__ bv, const float* __restrict__ eps,
    float* __restrict__ z, int b0)
{
    int idx = blockIdx.x * 256 + threadIdx.x;
    int img = idx >> 7, c = idx & 127;
    const float* p = part + (size_t)img * 2048;
    float sm = 0.f, sv = 0.f;
#pragma unroll
    for (int s = 0; s < 8; ++s) { sm += p[s * 256 + c]; sv += p[s * 256 + 128 + c]; }
    float zm = fmaxf(sm + bm[c], 0.0f);
    float zlv = fmaxf(sv + bv[c], 0.0f);
    z[idx] = zm + expf(0.5f * zlv) * eps[(size_t)(b0 + img) * 128 + c];
}

// ---------------- generic K=128 GEMM: out = act(A[M,128]@W[128,N]+b), opt BN --
__global__ __launch_bounds__(256) void k_gemm128(
    const float* __restrict__ A, const float* __restrict__ W,
    const float* __restrict__ bias,
    const float* __restrict__ g, const float* __restrict__ be,
    const float* __restrict__ mm, const float* __restrict__ vv,
    float* __restrict__ out, int N, int M)
{
    __shared__ __align__(16) float sAt[64 * 68];
    __shared__ __align__(16) float sB[64 * 68];
    int t = threadIdx.x;
    int tx = t & 15, ty = t >> 4;
    int row0 = blockIdx.x * 64, col0 = blockIdx.y * 64;
    float acc[16];
#pragma unroll
    for (int i = 0; i < 16; ++i) acc[i] = 0.0f;
    for (int kc = 0; kc < 128; kc += 64) {
        for (int i = t; i < 4096; i += 256) {
            int r = i >> 6, k = i & 63;
            sAt[k * 68 + r] = (row0 + r < M) ? A[(size_t)(row0 + r) * 128 + kc + k] : 0.0f;
        }
        for (int i = t; i < 4096; i += 256) {
            int k = i >> 6, c = i & 63;
            sB[k * 68 + c] = W[(size_t)(kc + k) * N + col0 + c];
        }
        __syncthreads();
#pragma unroll 8
        for (int k = 0; k < 64; ++k) {
            float a[4], b[4];
            *(float4*)a = *(const float4*)&sAt[k * 68 + ty * 4];
            *(float4*)b = *(const float4*)&sB[k * 68 + tx * 4];
#pragma unroll
            for (int i = 0; i < 4; ++i)
#pragma unroll
                for (int j = 0; j < 4; ++j)
                    acc[i * 4 + j] = fmaf(a[i], b[j], acc[i * 4 + j]);
        }
        __syncthreads();
    }
    int c0 = col0 + tx * 4;
    float bvv[4];
    *(float4*)bvv = *(const float4*)&bias[c0];
    float sc[4], bi[4];
    bool has_bn = (g != nullptr);
    if (has_bn) {
#pragma unroll
        for (int j = 0; j < 4; ++j) {
            float s = bn_fold_scale(g[c0 + j], vv[c0 + j]);
            sc[j] = s; bi[j] = be[c0 + j] - mm[c0 + j] * s;
        }
    }
#pragma unroll
    for (int i = 0; i < 4; ++i) {
        int row = row0 + ty * 4 + i;
        if (row >= M) continue;
        float ov[4];
#pragma unroll
        for (int j = 0; j < 4; ++j) {
            float r = fmaxf(acc[i * 4 + j] + bvv[j], 0.0f);
            ov[j] = has_bn ? fmaf(r, sc[j], bi[j]) : r;
        }
        *(float4*)&out[(size_t)row * N + c0] = *(float4*)ov;
    }
}

// ====== convT2 img-pair fused: [B,8,8,128] -> [B,16,16,64], 4 img/block ======
template <int RY, int RX>
__device__ __forceinline__ void ct2g_body(
    const float* __restrict__ in0, const float* __restrict__ w,
    float* __restrict__ sA, float* __restrict__ sW,
    const float* __restrict__ sB, const float* __restrict__ sS,
    const float* __restrict__ sBi, float* __restrict__ out0)
{
    constexpr int NTY = RY ? 1 : 2;
    constexpr int NTX = RX ? 1 : 2;
    constexpr int TT = NTY * NTX;
    int t = threadIdx.x;
    int px0 = (t & 1) * 4;
    int py  = (t >> 1) & 7;
    int u   = (t >> 4) & 1;
    int ty  = t >> 5;            // 8 co-groups of 8
    int co0 = ty * 8;
    int imgA = 2 * u, imgB = 2 * u + 1;
    float acc0[4][8], acc1[4][8];
#pragma unroll
    for (int i = 0; i < 4; ++i)
#pragma unroll
        for (int j = 0; j < 8; ++j) { acc0[i][j] = 0.0f; acc1[i][j] = 0.0f; }

    for (int pass = 0; pass < 8; ++pass) {
        int ci0 = pass * 16;
        __syncthreads();
        for (int img = 0; img < 4; ++img) {
            const float* xin = in0 + (size_t)img * 8192;
            for (int i = t; i < 16 * 81; i += 256) {
                int ci = i & 15, pix = i >> 4;
                int r = pix / 9, c = pix - r * 9;
                int iy = r - 1, ix = c - 1;
                float v = (iy >= 0 && ix >= 0) ? xin[(iy * 8 + ix) * 128 + ci0 + ci] : 0.0f;
                sA[(img * 16 + ci) * 81 + pix] = v;
            }
        }
        for (int tb = 0; tb < TT; tb += 2) {
            if (tb) __syncthreads();
            for (int i = t; i < 2 * 16 * 64; i += 256) {
                int kk = i >> 6, co = i & 63;
                int tl = kk >> 4, ci = kk & 15;
                int tt = tb + tl; if (tt >= TT) tt = TT - 1;
                int kh = RY ? 1 : 2 * (tt / NTX);
                int kw = RX ? 1 : 2 * (tt % NTX);
                sW[kk * 64 + co] = w[((size_t)(kh * 3 + kw) * 128 + ci0 + ci) * 64 + co];
            }
            __syncthreads();
#pragma unroll
            for (int tl = 0; tl < 2; ++tl) {
                int tt = tb + tl;
                if (tt >= TT) break;
                int tY = tt / NTX, tX = tt % NTX;
                int r = RY ? (py + 1) : (py + tY);
                int cb = RX ? (px0 + 1) : (px0 + tX);
                int aB = r * 9 + cb;
#pragma unroll 4
                for (int ci = 0; ci < 16; ++ci) {
                    float b[8];
                    *(float4*)&b[0] = *(const float4*)&sW[(tl * 16 + ci) * 64 + co0];
                    *(float4*)&b[4] = *(const float4*)&sW[(tl * 16 + ci) * 64 + co0 + 4];
                    float a0[4], a1[4];
                    const float* pA = &sA[(imgA * 16 + ci) * 81 + aB];
                    const float* pB = &sA[(imgB * 16 + ci) * 81 + aB];
                    a0[0] = pA[0]; a0[1] = pA[1]; a0[2] = pA[2]; a0[3] = pA[3];
                    a1[0] = pB[0]; a1[1] = pB[1]; a1[2] = pB[2]; a1[3] = pB[3];
#pragma unroll
                    for (int i = 0; i < 4; ++i)
#pragma unroll
                        for (int j = 0; j < 8; ++j) {
                            acc0[i][j] = fmaf(a0[i], b[j], acc0[i][j]);
                            acc1[i][j] = fmaf(a1[i], b[j], acc1[i][j]);
                        }
                }
            }
        }
    }
#pragma unroll
    for (int l = 0; l < 2; ++l) {
        int img = 2 * u + l;
        float* oimg = out0 + (size_t)img * 16384;
#pragma unroll
        for (int i = 0; i < 4; ++i) {
            int oy = 2 * py + RY, ox = 2 * (px0 + i) + RX;
            float* o = oimg + (oy * 16 + ox) * 64 + co0;
            float ov0[4], ov1[4];
#pragma unroll
            for (int j = 0; j < 4; ++j) {
                int c = co0 + j;
                float r = fmaxf((l ? acc1[i][j] : acc0[i][j]) + sB[c], 0.0f);
                ov0[j] = fmaf(r, sS[c], sBi[c]);
            }
#pragma unroll
            for (int j = 0; j < 4; ++j) {
                int c = co0 + 4 + j;
                float r = fmaxf((l ? acc1[i][4 + j] : acc0[i][4 + j]) + sB[c], 0.0f);
                ov1[j] = fmaf(r, sS[c], sBi[c]);
            }
            *(float4*)o = *(float4*)ov0;
            *(float4*)(o + 4) = *(float4*)ov1;
        }
    }
}

__global__ __launch_bounds__(256, 4) void k_ct2g(
    const float* __restrict__ in, const float* __restrict__ w,
    const float* __restrict__ bias,
    const float* __restrict__ g, const float* __restrict__ be,
    const float* __restrict__ mm, const float* __restrict__ vv,
    float* __restrict__ out)
{
    __shared__ __align__(16) float sA[4 * 16 * 81];
    __shared__ __align__(16) float sW[2 * 16 * 64];
    __shared__ __align__(16) float sB[64], sS[64], sBi[64];
    int t = threadIdx.x;
    if (t < 64) {
        float sc = bn_fold_scale(g[t], vv[t]);
        sS[t] = sc; sBi[t] = be[t] - mm[t] * sc; sB[t] = bias[t];
    }
    const float* in0 = in + (size_t)blockIdx.x * 4 * 8192;
    float* out0 = out + (size_t)blockIdx.x * 4 * 16384;
    switch (blockIdx.y) {
        case 0:  ct2g_body<0,0>(in0, w, sA, sW, sB, sS, sBi, out0); break;
        case 1:  ct2g_body<0,1>(in0, w, sA, sW, sB, sS, sBi, out0); break;
        case 2:  ct2g_body<1,0>(in0, w, sA, sW, sB, sS, sBi, out0); break;
        default: ct2g_body<1,1>(in0, w, sA, sW, sB, sS, sBi, out0); break;
    }
}

// ====== convT3 img-pair fused: [B,16,16,64] -> [B,32,32,32], 2 img/block =====
template <int RY, int RX>
__device__ __forceinline__ void ct3g_body(
    const float* __restrict__ in0, const float* __restrict__ w,
    float* __restrict__ sA, float* __restrict__ sW,
    const float* __restrict__ sB, const float* __restrict__ sS,
    const float* __restrict__ sBi, float* __restrict__ out0)
{
    constexpr int NTY = RY ? 1 : 2;
    constexpr int NTX = RX ? 1 : 2;
    constexpr int TT = NTY * NTX;
    int t = threadIdx.x;
    int px0 = (t & 3) * 4;
    int py  = (t >> 2) & 15;
    int ty  = t >> 6;            // 4 co-groups of 8
    int co0 = ty * 8;
    float acc0[4][8], acc1[4][8];
#pragma unroll
    for (int i = 0; i < 4; ++i)
#pragma unroll
        for (int j = 0; j < 8; ++j) { acc0[i][j] = 0.0f; acc1[i][j] = 0.0f; }

    for (int pass = 0; pass < 8; ++pass) {
        int ci0 = pass * 8;
        __syncthreads();
        for (int img = 0; img < 2; ++img) {
            const float* xin = in0 + (size_t)img * 16384;
            for (int i = t; i < 8 * 289; i += 256) {
                int ci = i & 7, pix = i >> 3;
                int r = pix / 17, c = pix - r * 17;
                int iy = r - 1, ix = c - 1;
                float v = (iy >= 0 && ix >= 0) ? xin[(iy * 16 + ix) * 64 + ci0 + ci] : 0.0f;
                sA[(img * 8 + ci) * 289 + pix] = v;
            }
        }
        for (int tb = 0; tb < TT; tb += 2) {
            if (tb) __syncthreads();
            for (int i = t; i < 2 * 8 * 32; i += 256) {
                int kk = i >> 5, co = i & 31;
                int tl = kk >> 3, ci = kk & 7;
                int tt = tb + tl; if (tt >= TT) tt = TT - 1;
                int kh = RY ? 1 : 2 * (tt / NTX);
                int kw = RX ? 1 : 2 * (tt % NTX);
                sW[kk * 32 + co] = w[((size_t)(kh * 3 + kw) * 64 + ci0 + ci) * 32 + co];
            }
            __syncthreads();
#pragma unroll
            for (int tl = 0; tl < 2; ++tl) {
                int tt = tb + tl;
                if (tt >= TT) break;
                int tY = tt / NTX, tX = tt % NTX;
                int r = RY ? (py + 1) : (py + tY);
                int cb = RX ? (px0 + 1) : (px0 + tX);
                int aB = r * 17 + cb;
#pragma unroll 4
                for (int ci = 0; ci < 8; ++ci) {
                    float b[8];
                    *(float4*)&b[0] = *(const float4*)&sW[(tl * 8 + ci) * 32 + co0];
                    *(float4*)&b[4] = *(const float4*)&sW[(tl * 8 + ci) * 32 + co0 + 4];
                    float a0[4], a1[4];
                    const float* pA = &sA[ci * 289 + aB];
                    const float* pB = &sA[(8 + ci) * 289 + aB];
                    a0[0] = pA[0]; a0[1] = pA[1]; a0[2] = pA[2]; a0[3] = pA[3];
                    a1[0] = pB[0]; a1[1] = pB[1]; a1[2] = pB[2]; a1[3] = pB[3];
#pragma unroll
                    for (int i = 0; i < 4; ++i)
#pragma unroll
                        for (int j = 0; j < 8; ++j) {
                            acc0[i][j] = fmaf(a0[i], b[j], acc0[i][j]);
                            acc1[i][j] = fmaf(a1[i], b[j], acc1[i][j]);
                        }
                }
            }
        }
    }
#pragma unroll
    for (int l = 0; l < 2; ++l) {
        float* oimg = out0 + (size_t)l * 32768;
#pragma unroll
        for (int i = 0; i < 4; ++i) {
            int oy = 2 * py + RY, ox = 2 * (px0 + i) + RX;
            float* o = oimg + (oy * 32 + ox) * 32 + co0;
            float ov0[4], ov1[4];
#pragma unroll
            for (int j = 0; j < 4; ++j) {
                int c = co0 + j;
                float r = fmaxf((l ? acc1[i][j] : acc0[i][j]) + sB[c], 0.0f);
                ov0[j] = fmaf(r, sS[c], sBi[c]);
            }
#pragma unroll
            for (int j = 0; j < 4; ++j) {
                int c = co0 + 4 + j;
                float r = fmaxf((l ? acc1[i][4 + j] : acc0[i][4 + j]) + sB[c], 0.0f);
                ov1[j] = fmaf(r, sS[c], sBi[c]);
            }
            *(float4*)o = *(float4*)ov0;
            *(float4*)(o + 4) = *(float4*)ov1;
        }
    }
}

__global__ __launch_bounds__(256, 4) void k_ct3g(
    const float* __restrict__ in, const float* __restrict__ w,
    const float* __restrict__ bias,
    const float* __restrict__ g, const float* __restrict__ be,
    const float* __restrict__ mm, const float* __restrict__ vv,
    float* __restrict__ out)
{
    __shared__ __align__(16) float sA[2 * 8 * 289];
    __shared__ __align__(16) float sW[2 * 8 * 32];
    __shared__ __align__(16) float sB[32], sS[32], sBi[32];
    int t = threadIdx.x;
    if (t < 32) {
        float sc = bn_fold_scale(g[t], vv[t]);
        sS[t] = sc; sBi[t] = be[t] - mm[t] * sc; sB[t] = bias[t];
    }
    const float* in0 = in + (size_t)blockIdx.x * 2 * 16384;
    float* out0 = out + (size_t)blockIdx.x * 2 * 32768;
    switch (blockIdx.y) {
        case 0:  ct3g_body<0,0>(in0, w, sA, sW, sB, sS, sBi, out0); break;
        case 1:  ct3g_body<0,1>(in0, w, sA, sW, sB, sS, sBi, out0); break;
        case 2:  ct3g_body<1,0>(in0, w, sA, sW, sB, sS, sBi, out0); break;
        default: ct3g_body<1,1>(in0, w, sA, sW, sB, sS, sBi, out0); break;
    }
}

// ---------------- convT4 + sigmoid + error: [B,32,32,32] -> err [Bc,32,32] ----
__global__ __launch_bounds__(256) void k_convT4_err(
    const float* __restrict__ in, const float* __restrict__ w,
    const float* __restrict__ b, const float* __restrict__ x,
    float* __restrict__ err, int b0)
{
    __shared__ __align__(16) float sIn[32 * 342];
    int t = threadIdx.x;
    int quart = blockIdx.x, img = blockIdx.y;
    int r0 = quart * 8;
    const float* xin = in + (size_t)img * 32768;
    for (int i = t; i < 10880; i += 256) {
        int pix = i >> 5, ci = i & 31;
        int lr = pix / 34;
        int cx = pix - lr * 34 - 1;
        int gy = r0 - 1 + lr;
        float v = (((unsigned)gy < 32u) && ((unsigned)cx < 32u))
                      ? xin[(gy * 32 + cx) * 32 + ci] : 0.0f;
        sIn[ci * 342 + pix] = v;
    }
    __syncthreads();
    int ly = t >> 5, lx = t & 31;
    float a0 = 0.f, a1 = 0.f, a2 = 0.f;
#pragma unroll
    for (int kh = 0; kh < 3; ++kh)
#pragma unroll
        for (int kw = 0; kw < 3; ++kw) {
            int pix = (ly + kh) * 34 + (lx + kw);
            const float* wp = w + ((kh * 3 + kw) * 32) * 3;
#pragma unroll 4
            for (int ci = 0; ci < 32; ++ci) {
                float v = sIn[ci * 342 + pix];
                a0 = fmaf(v, wp[ci * 3 + 0], a0);
                a1 = fmaf(v, wp[ci * 3 + 1], a1);
                a2 = fmaf(v, wp[ci * 3 + 2], a2);
            }
        }
    float s0 = 1.0f / (1.0f + expf(-(a0 + b[0])));
    float s1 = 1.0f / (1.0f + expf(-(a1 + b[1])));
    float s2 = 1.0f / (1.0f + expf(-(a2 + b[2])));
    int oy = r0 + ly;
    size_t xi = (((size_t)(b0 + img) * 32 + oy) * 32 + lx) * 3;
    float d0 = x[xi + 0] - s0;
    float d1 = x[xi + 1] - s1;
    float d2 = x[xi + 2] - s2;
    err[(size_t)img * 1024 + oy * 32 + lx] = (d0 * d0 + d1 * d1 + d2 * d2) * (1.0f / 3.0f);
}

// ---------------- Otsu + mask (per-chunk) ----------------
__global__ __launch_bounds__(256) void k_otsu(
    const float* __restrict__ err, int* __restrict__ mask)
{
    __shared__ float sE[1024];
    __shared__ float sRed[4];
    __shared__ float sSig[96];
    __shared__ float sThr;
    int img = blockIdx.x, t = threadIdx.x;
    const float* e = err + (size_t)img * 1024;
    float part = 0.f;
    for (int i = t; i < 1024; i += 256) { float v = e[i]; sE[i] = v; part += v; }
    for (int o = 32; o; o >>= 1) part += __shfl_down(part, o);
    if ((t & 63) == 0) sRed[t >> 6] = part;
    __syncthreads();
    float tot = sRed[0] + sRed[1] + sRed[2] + sRed[3];
    if (t < 91) {
        float T = (float)((double)t * 0.01);
        int c = 0; float s = 0.f;
        for (int i = 0; i < 1024; ++i) {
            float v = sE[i];
            bool lt = v < T;
            c += lt ? 1 : 0;
            s += lt ? v : 0.0f;
        }
        float cf = (float)c;
        float p0 = cf * (1.0f / 1024.0f);
        float p1 = 1.0f - p0;
        float m0 = s / fmaxf(cf, 1.0f);
        float m1 = (tot - s) / fmaxf(1024.0f - cf, 1.0f);
        float d = m0 - m1;
        sSig[t] = (c > 0 && c < 1024) ? (p0 * p1) * (d * d) : 0.0f;
    }
    __syncthreads();
    if (t == 0) {
        float best = sSig[0]; int bk = 0;
        for (int k = 1; k < 91; ++k)
            if (sSig[k] > best) { best = sSig[k]; bk = k; }
        sThr = (float)((double)bk * 0.01);
    }
    __syncthreads();
    float thr = sThr;
    int* m = mask + (size_t)img * 1024;
    for (int i = t; i < 1024; i += 256) m[i] = (sE[i] < thr) ? 1 : 0;
}

// ---------------- launch ----------------
extern "C" void kernel_launch(void* const* d_in, const int* in_sizes, int n_in,
                              void* d_out, int out_size, void* d_ws, size_t ws_size,
                              hipStream_t stream)
{
    (void)in_sizes; (void)out_size;
    const float* p[46];
    bool flat = (n_in >= 46);
    if (flat) {
        for (int i = 0; i < 46; ++i) p[i] = (const float*)d_in[i];
    } else {
        int o = 0;
        int s = 0;
        auto leaf = [&](int count) {
            for (int j = 0; j < count; ++j) p[o++] = (const float*)d_in[s++];
        };
        auto bn4 = [&](int C) {
            const float* base = (const float*)d_in[s++];
            p[o++] = base; p[o++] = base + C; p[o++] = base + 2 * C; p[o++] = base + 3 * C;
        };
        leaf(2);            // x, eps_z
        leaf(2); bn4(32);   // e_w1, e_b1, e_bn1
        leaf(2); bn4(64);   // e_w2, e_b2, e_bn2
        leaf(2); bn4(128);  // e_w3, e_b3, e_bn3
        leaf(4);            // e_wm, e_bm, e_wv, e_bv
        leaf(2);            // d_wd, d_bd
        leaf(2); bn4(128);  // d_w1, d_b1, d_bn1
        leaf(2); bn4(64);   // d_w2, d_b2, d_bn2
        leaf(2); bn4(32);   // d_w3, d_b3, d_bn3
        leaf(2);            // d_w4, d_b4
    }
    const float* x      = p[0];
    const float* epsz   = p[1];
    const float* e_w1   = p[2];
    const float* e_b1   = p[3];
    const float* e_bn1g = p[4], *e_bn1b = p[5], *e_bn1m = p[6], *e_bn1v = p[7];
    const float* e_w2   = p[8];
    const float* e_b2   = p[9];
    const float* e_bn2g = p[10], *e_bn2b = p[11], *e_bn2m = p[12], *e_bn2v = p[13];
    const float* e_w3   = p[14];
    const float* e_b3   = p[15];
    const float* e_bn3g = p[16], *e_bn3b = p[17], *e_bn3m = p[18], *e_bn3v = p[19];
    const float* e_wm   = p[20];
    const float* e_bm   = p[21];
    const float* e_wv   = p[22];
    const float* e_bv   = p[23];
    const float* d_wd   = p[24];
    const float* d_bd   = p[25];
    const float* d_w1   = p[26];
    const float* d_b1   = p[27];
    const float* d_bn1g = p[28], *d_bn1b = p[29], *d_bn1m = p[30], *d_bn1v = p[31];
    const float* d_w2   = p[32];
    const float* d_b2   = p[33];
    const float* d_bn2g = p[34], *d_bn2b = p[35], *d_bn2m = p[36], *d_bn2v = p[37];
    const float* d_w3   = p[38];
    const float* d_b3   = p[39];
    const float* d_bn3g = p[40], *d_bn3b = p[41], *d_bn3m = p[42], *d_bn3v = p[43];
    const float* d_w4   = p[44];
    const float* d_b4   = p[45];
    int* mask = (int*)d_out;

    float* ws = (float*)d_ws;
    int Bc = B_TOTAL;
    while (Bc > 16) {
        size_t need = (size_t)Bc * 50304u * 4u;
        if (need <= ws_size) break;
        Bc >>= 1;
    }
    float* err = ws;
    float* z   = err + (size_t)Bc * 1024;
    float* P   = z + (size_t)Bc * 128;
    float* Q   = P + (size_t)Bc * 16384;

    for (int b0 = 0; b0 < B_TOTAL; b0 += Bc) {
        k_conv1<<<Bc, 256, 0, stream>>>(x, e_w1, e_b1, e_bn1g, e_bn1b, e_bn1m, e_bn1v, P, b0);
        k_c2g<<<Bc / 2, 256, 0, stream>>>(P, e_w2, e_b2, e_bn2g, e_bn2b, e_bn2m, e_bn2v, Q);
        k_c3g<<<Bc / 4, 256, 0, stream>>>(Q, e_w3, e_b3, e_bn3g, e_bn3b, e_bn3m, e_bn3v, P);
        k_zpart<<<dim3(Bc / 16, 8), 256, 0, stream>>>(P, e_wm, e_wv, Q);
        k_zcombine<<<(Bc * 128) / 256, 256, 0, stream>>>(Q, e_bm, e_bv, epsz, z, b0);
        k_gemm128<<<dim3((Bc + 63) / 64, 128), 256, 0, stream>>>(z, d_wd, d_bd,
            nullptr, nullptr, nullptr, nullptr, P, 8192, Bc);
        k_gemm128<<<dim3(Bc, 2), 256, 0, stream>>>(P, d_w1, d_b1,
            d_bn1g, d_bn1b, d_bn1m, d_bn1v, Q, 128, Bc * 64);
        k_ct2g<<<dim3(Bc / 4, 4), 256, 0, stream>>>(Q, d_w2, d_b2, d_bn2g, d_bn2b, d_bn2m, d_bn2v, P);
        k_ct3g<<<dim3(Bc / 2, 4), 256, 0, stream>>>(P, d_w3, d_b3, d_bn3g, d_bn3b, d_bn3m, d_bn3v, Q);
        k_convT4_err<<<dim3(4, Bc), 256, 0, stream>>>(Q, d_w4, d_b4, x, err, b0);
        k_otsu<<<Bc, 256, 0, stream>>>(err, mask + (size_t)b0 * 1024);
    }
}